// Round 7
// baseline (1466.422 us; speedup 1.0000x reference)
//
#include <hip/hip_runtime.h>
#include <hip/hip_bf16.h>

#define DEV static __device__ __forceinline__

typedef short s16x8 __attribute__((ext_vector_type(8)));
typedef float f32x4 __attribute__((ext_vector_type(4)));
typedef unsigned short u16;

constexpr int Bn = 64, Pn = 196, ENCn = 2048, EMBn = 512, DECn = 512, ATTn = 512;
constexpr int VOCABn = 10000, Sn = 20;

DEV u16 f2bf(float x) {
  union { float f; unsigned u; } v; v.f = x;
  unsigned r = v.u + 0x7fffu + ((v.u >> 16) & 1u);
  return (u16)(r >> 16);
}
DEV float bf2f(u16 b) {
  union { unsigned u; float f; } v; v.u = ((unsigned)b) << 16;
  return v.f;
}
DEV float sigm(float x) { return 1.f / (1.f + __expf(-x)); }
DEV float tanh_fast(float x) {
  float e = __expf(2.f * x);
  return 1.f - 2.f / (e + 1.f);
}

DEV s16x8 ld8(const u16* p) { return *reinterpret_cast<const s16x8*>(p); }
DEV s16x8 ld8(const float* p) {
  s16x8 r;
#pragma unroll
  for (int j = 0; j < 8; j++) r[j] = (short)f2bf(p[j]);
  return r;
}
DEV f32x4 mfma(s16x8 a, s16x8 b, f32x4 c) {
  return __builtin_amdgcn_mfma_f32_16x16x32_bf16(a, b, c, 0, 0, 0);
}

#define GLOAD_LDS16(gsrc, ldst)                                                \
  __builtin_amdgcn_global_load_lds(                                            \
      (const __attribute__((address_space(1))) void*)(gsrc),                   \
      (__attribute__((address_space(3))) void*)(ldst), 16, 0, 0)

// ---------------- ONE prep kernel: feat cvt+partial mean, all weight cvts, wdecT
// blocks 0..447: feat chunks (b = bx/7, px = bx%7). blocks 448+: grid-stride cvts.
__global__ __launch_bounds__(256) void k_prep(
    const float* __restrict__ feat, u16* __restrict__ featbf, float* __restrict__ pavg,
    const float* __restrict__ wenc_w, u16* __restrict__ wenc_bf,
    const float* __restrict__ wdec_w, u16* __restrict__ wdec_bf, u16* __restrict__ wdecT,
    const float* __restrict__ Wih_w, u16* __restrict__ Wih_bf,
    const float* __restrict__ Whh_w, u16* __restrict__ Whh_bf,
    const float* __restrict__ fcw_w, u16* __restrict__ fcw_bf) {
  int tid = threadIdx.x;
  if (blockIdx.x < 448) {
    int b = blockIdx.x / 7, px = blockIdx.x % 7;
    int d8 = tid * 8;
    const float* p = feat + ((size_t)b * Pn + px * 28) * ENCn + d8;
    u16* q = featbf + ((size_t)b * Pn + px * 28) * ENCn + d8;
    float acc[8] = {};
    for (int k = 0; k < 28; k++) {
      float4 v0 = *(const float4*)(p + (size_t)k * ENCn);
      float4 v1 = *(const float4*)(p + (size_t)k * ENCn + 4);
      acc[0] += v0.x; acc[1] += v0.y; acc[2] += v0.z; acc[3] += v0.w;
      acc[4] += v1.x; acc[5] += v1.y; acc[6] += v1.z; acc[7] += v1.w;
      s16x8 o;
      o[0] = (short)f2bf(v0.x); o[1] = (short)f2bf(v0.y);
      o[2] = (short)f2bf(v0.z); o[3] = (short)f2bf(v0.w);
      o[4] = (short)f2bf(v1.x); o[5] = (short)f2bf(v1.y);
      o[6] = (short)f2bf(v1.z); o[7] = (short)f2bf(v1.w);
      *(s16x8*)(q + (size_t)k * ENCn) = o;
    }
    float* pp = pavg + ((size_t)px * Bn + b) * ENCn + d8;
    *(f32x4*)pp = f32x4{acc[0], acc[1], acc[2], acc[3]};
    *(f32x4*)(pp + 4) = f32x4{acc[4], acc[5], acc[6], acc[7]};
    return;
  }
  int gid = (blockIdx.x - 448) * 256 + tid;
  int stride = (gridDim.x - 448) * 256;
  auto run = [&](const float* __restrict__ s, u16* __restrict__ d, int n8) {
    for (int i = gid; i < n8; i += stride) {
      const float4* sp = (const float4*)(s + (size_t)i * 8);
      float4 a = sp[0], b = sp[1];
      s16x8 o;
      o[0] = (short)f2bf(a.x); o[1] = (short)f2bf(a.y);
      o[2] = (short)f2bf(a.z); o[3] = (short)f2bf(a.w);
      o[4] = (short)f2bf(b.x); o[5] = (short)f2bf(b.y);
      o[6] = (short)f2bf(b.z); o[7] = (short)f2bf(b.w);
      *(s16x8*)(d + (size_t)i * 8) = o;
    }
  };
  run(wenc_w, wenc_bf, 131072);   // 512*2048
  run(wdec_w, wdec_bf, 32768);    // 512*512
  run(Wih_w, Wih_bf, 655360);     // 2048*2560
  run(Whh_w, Whh_bf, 131072);     // 2048*512
  run(fcw_w, fcw_bf, 640000);     // 10000*512
  // wdecT[k][n] = wdec[n][k]
  for (int i = gid; i < 262144; i += stride) {
    int n = i >> 9, k = i & 511;
    wdecT[(size_t)k * 512 + n] = f2bf(wdec_w[i]);
  }
}

// ---------------- final mean reduce: avg = sum(pavg[0..6]) / 196 --------------
__global__ __launch_bounds__(256) void k_avg_final(
    const float* __restrict__ pavg, float* __restrict__ avg) {
  int idx = blockIdx.x * 256 + threadIdx.x;   // over 32768 float4s
  int b = idx >> 9, e4 = (idx & 511) * 4;
  float4 s = {0.f, 0.f, 0.f, 0.f};
#pragma unroll
  for (int px = 0; px < 7; px++) {
    float4 v = *(const float4*)(pavg + ((size_t)px * Bn + b) * ENCn + e4);
    s.x += v.x; s.y += v.y; s.z += v.z; s.w += v.w;
  }
  float4 o = { s.x * (1.f/196.f), s.y * (1.f/196.f), s.z * (1.f/196.f), s.w * (1.f/196.f) };
  *(float4*)(avg + (size_t)b * ENCn + e4) = o;
}

// ---------------- h0 + c0 in one launch (64 blocks) ---------------------------
__global__ __launch_bounds__(256) void k_h0c0(
    const float* __restrict__ avg,
    const float* __restrict__ h0w, const float* __restrict__ h0b,
    const float* __restrict__ c0w, const float* __restrict__ c0b,
    u16* __restrict__ h0out, float* __restrict__ c0out) {
  int wid = threadIdx.x >> 6, lane = threadIdx.x & 63;
  int r = lane & 15, hi = lane >> 4;
  bool isC = blockIdx.x >= 32;
  int n0 = ((int)blockIdx.x & 31) * 16;
  const float* W = (isC ? c0w : h0w) + (size_t)(n0 + r) * ENCn + hi * 8;
  const float* ap = avg + (size_t)(wid * 16 + r) * ENCn + hi * 8;
  f32x4 acc = {0.f, 0.f, 0.f, 0.f};
  for (int k = 0; k < ENCn; k += 32) acc = mfma(ld8(ap + k), ld8(W + k), acc);
  int col = n0 + r;
  float bb = (isC ? c0b : h0b)[col];
#pragma unroll
  for (int j = 0; j < 4; j++) {
    int row = wid * 16 + hi * 4 + j;
    float v = fmaxf(acc[j] + bb, 0.f);
    if (isC) c0out[(size_t)row * DECn + col] = v;
    else     h0out[(size_t)row * DECn + col] = f2bf(v);
  }
}

// ---------------- generic skinny GEMM (used once for decp0) -------------------
template<typename TA, typename TW, int K>
__global__ __launch_bounds__(256) void k_lin64(
    const TA* __restrict__ A, const TW* __restrict__ W,
    const float* __restrict__ bias1, float* __restrict__ outF, size_t ldo) {
  int wid = threadIdx.x >> 6, lane = threadIdx.x & 63;
  int r = lane & 15, hi = lane >> 4;
  int n0 = blockIdx.x * 16;
  const TA* ap = A + (size_t)(wid * 16 + r) * K + hi * 8;
  const TW* wp = W + (size_t)(n0 + r) * K + hi * 8;
  f32x4 acc = {0.f, 0.f, 0.f, 0.f};
  for (int k = 0; k < K; k += 32) acc = mfma(ld8(ap + k), ld8(wp + k), acc);
  int col = n0 + r;
  float bb = bias1[col];
#pragma unroll
  for (int j = 0; j < 4; j++) {
    int row = wid * 16 + hi * 4 + j;
    outF[(size_t)row * ldo + col] = acc[j] + bb;
  }
}

// ---------------- enc_proj: 128x128 tile, BK=32, global_load_lds, bf16 out ----
__global__ __launch_bounds__(256) void k_encproj(
    const u16* __restrict__ Abf, const u16* __restrict__ Wbf,
    const float* __restrict__ bias, u16* __restrict__ out) {
  __shared__ u16 As[128][32];
  __shared__ u16 Bs[128][32];
  int tid = threadIdx.x;
  int wid = tid >> 6, lane = tid & 63, r = lane & 15, hi = lane >> 4;
  int wm = wid >> 1, wn = wid & 1;
  int m0 = blockIdx.y * 128, n0 = blockIdx.x * 128;
  int srow = tid >> 2, scol = (tid & 3) * 8;
  const u16* ga = Abf + (size_t)(m0 + srow) * ENCn + scol;
  const u16* gb = Wbf + (size_t)(n0 + srow) * ENCn + scol;
  u16* As1 = &As[0][0];
  u16* Bs1 = &Bs[0][0];
  f32x4 acc[4][4] = {};
  for (int k0 = 0; k0 < ENCn; k0 += 32) {
    GLOAD_LDS16(ga + k0,                      As1 + wid * 512);
    GLOAD_LDS16(ga + k0 + (size_t)64 * ENCn,  As1 + 2048 + wid * 512);
    GLOAD_LDS16(gb + k0,                      Bs1 + wid * 512);
    GLOAD_LDS16(gb + k0 + (size_t)64 * ENCn,  Bs1 + 2048 + wid * 512);
    __syncthreads();
    s16x8 af[4], bfr[4];
#pragma unroll
    for (int i = 0; i < 4; i++) af[i]  = *(const s16x8*)(As1 + (wm * 64 + i * 16 + r) * 32 + hi * 8);
#pragma unroll
    for (int j = 0; j < 4; j++) bfr[j] = *(const s16x8*)(Bs1 + (wn * 64 + j * 16 + r) * 32 + hi * 8);
#pragma unroll
    for (int i = 0; i < 4; i++)
#pragma unroll
      for (int j = 0; j < 4; j++)
        acc[i][j] = mfma(af[i], bfr[j], acc[i][j]);
    __syncthreads();
  }
#pragma unroll
  for (int i = 0; i < 4; i++)
#pragma unroll
    for (int j = 0; j < 4; j++) {
      int col = n0 + wn * 64 + j * 16 + r;
      float bb = bias[col];
#pragma unroll
      for (int q = 0; q < 4; q++) {
        int row = m0 + wm * 64 + i * 16 + hi * 4 + q;
        out[(size_t)row * 512 + col] = f2bf(acc[i][j][q] + bb);
      }
    }
}

// ---------------- attn + (emb,h) gates slice, heterogeneous grid (51,64) ------
// bx<49: attention wave per (b,p). bx 49..50: gates slice K=1024 -> part[2].
__global__ __launch_bounds__(256) void k_attn_plus(
    const u16* __restrict__ encp, const float* __restrict__ decp,
    const float* __restrict__ Vw, const float* __restrict__ Vb,
    float* __restrict__ e,
    const float* __restrict__ embw, const int* __restrict__ caps, int t,
    const u16* __restrict__ hin, const u16* __restrict__ Wih,
    const u16* __restrict__ Whh, float* __restrict__ part) {
  int bx = blockIdx.x, by = blockIdx.y;
  int wid = threadIdx.x >> 6, lane = threadIdx.x & 63;
  if (bx < 49) {
    int p = bx * 4 + wid, b = by;
    const float* dp = decp + (size_t)b * ATTn + lane * 8;
    float4 dv0 = *(const float4*)dp, dv1 = *(const float4*)(dp + 4);
    float4 vv0 = *(const float4*)(Vw + lane * 8), vv1 = *(const float4*)(Vw + lane * 8 + 4);
    s16x8 ev = *(const s16x8*)(encp + (((size_t)(b * Pn + p)) << 9) + lane * 8);
    float s = 0.f;
    s += vv0.x * tanh_fast(bf2f((u16)ev[0]) + dv0.x);
    s += vv0.y * tanh_fast(bf2f((u16)ev[1]) + dv0.y);
    s += vv0.z * tanh_fast(bf2f((u16)ev[2]) + dv0.z);
    s += vv0.w * tanh_fast(bf2f((u16)ev[3]) + dv0.w);
    s += vv1.x * tanh_fast(bf2f((u16)ev[4]) + dv1.x);
    s += vv1.y * tanh_fast(bf2f((u16)ev[5]) + dv1.y);
    s += vv1.z * tanh_fast(bf2f((u16)ev[6]) + dv1.z);
    s += vv1.w * tanh_fast(bf2f((u16)ev[7]) + dv1.w);
    for (int m = 32; m; m >>= 1) s += __shfl_xor(s, m);
    if (lane == 0) e[(size_t)b * Pn + p] = s + Vb[0];
  } else {
    int sb = (bx - 49) * 64 + by;          // 0..127
    int n0 = sb * 16;
    int r = lane & 15, hi = lane >> 4;
    int brow = wid * 16 + r;
    f32x4 acc = {0.f, 0.f, 0.f, 0.f};
    int id = caps[brow * Sn + t];
    const float* a = embw + (size_t)id * EMBn + hi * 8;
    const u16* w = Wih + (size_t)(n0 + r) * 2560 + 2048 + hi * 8;
#pragma unroll 4
    for (int k = 0; k < 512; k += 32) acc = mfma(ld8(a + k), ld8(w + k), acc);
    const u16* a2 = hin + (size_t)brow * DECn + hi * 8;
    const u16* w2 = Whh + (size_t)(n0 + r) * 512 + hi * 8;
#pragma unroll 4
    for (int k = 0; k < 512; k += 32) acc = mfma(ld8(a2 + k), ld8(w2 + k), acc);
#pragma unroll
    for (int j = 0; j < 4; j++) {
      int row = wid * 16 + hi * 4 + j;
      part[((size_t)2 * 64 + row) * 2048 + n0 + r] = acc[j];
    }
  }
}

// ---------------- softmax + ctx chunk, p-parallel, unrolled -------------------
__global__ __launch_bounds__(256) void k_ctx(
    const float* __restrict__ e, const u16* __restrict__ featbf,
    u16* __restrict__ ctxbf) {
  __shared__ float sw[Pn];
  __shared__ float red[256];
  __shared__ float pacc[4 * 512];
  int b = blockIdx.y, chunk = blockIdx.x, tid = threadIdx.x;
  float ev = (tid < Pn) ? e[(size_t)b * Pn + tid] : -3.0e38f;
  red[tid] = ev; __syncthreads();
  for (int s = 128; s > 0; s >>= 1) { if (tid < s) red[tid] = fmaxf(red[tid], red[tid + s]); __syncthreads(); }
  float m = red[0]; __syncthreads();
  float ex = (tid < Pn) ? __expf(ev - m) : 0.f;
  red[tid] = ex; __syncthreads();
  for (int s = 128; s > 0; s >>= 1) { if (tid < s) red[tid] += red[tid + s]; __syncthreads(); }
  float inv = 1.f / red[0];
  if (tid < Pn) sw[tid] = ex * inv;
  __syncthreads();
  int g = tid >> 6, t64 = tid & 63;
  int dloc = t64 * 8;
  const u16* fp = featbf + (size_t)b * Pn * ENCn + chunk * 512 + dloc;
  float acc[8] = {};
#pragma unroll 4
  for (int p = g; p < Pn; p += 4) {
    float w = sw[p];
    s16x8 v = *(const s16x8*)(fp + (size_t)p * ENCn);
#pragma unroll
    for (int j = 0; j < 8; j++) acc[j] += w * bf2f((u16)v[j]);
  }
#pragma unroll
  for (int j = 0; j < 8; j++) pacc[g * 512 + dloc + j] = acc[j];
  __syncthreads();
  int dd = tid * 2;
  float a0 = pacc[dd]       + pacc[512 + dd]     + pacc[1024 + dd]     + pacc[1536 + dd];
  float a1 = pacc[dd + 1]   + pacc[512 + dd + 1] + pacc[1024 + dd + 1] + pacc[1536 + dd + 1];
  unsigned pk = (unsigned)f2bf(a0) | ((unsigned)f2bf(a1) << 16);
  *(unsigned*)(ctxbf + (size_t)b * ENCn + chunk * 512 + dd) = pk;
}

// ---------------- gates ctx part: grid (128 n-blocks, 2 K-slices of 1024) -----
__global__ __launch_bounds__(256) void k_gates_ctx(
    const u16* __restrict__ ctxbf, const u16* __restrict__ Wih,
    float* __restrict__ part) {
  int wid = threadIdx.x >> 6, lane = threadIdx.x & 63;
  int r = lane & 15, hi = lane >> 4;
  int n0 = blockIdx.x * 16;
  int sl = blockIdx.y;
  int brow = wid * 16 + r;
  const u16* a = ctxbf + (size_t)brow * ENCn + sl * 1024 + hi * 8;
  const u16* w = Wih + (size_t)(n0 + r) * 2560 + sl * 1024 + hi * 8;
  f32x4 acc = {0.f, 0.f, 0.f, 0.f};
#pragma unroll 4
  for (int k = 0; k < 1024; k += 32) acc = mfma(ld8(a + k), ld8(w + k), acc);
#pragma unroll
  for (int j = 0; j < 4; j++) {
    int row = wid * 16 + hi * 4 + j;
    part[((size_t)sl * 64 + row) * 2048 + n0 + r] = acc[j];
  }
}

// ---------------- reduce(3) + LSTM pointwise + coalesced dec_proj -------------
// grid 64 blocks (one b), 512 thr.
__global__ __launch_bounds__(512) void k_lstm_decp(
    const float* __restrict__ part, const float* __restrict__ bih,
    const float* __restrict__ bhh, float* __restrict__ cbuf,
    u16* __restrict__ hnew, const u16* __restrict__ wdecT,
    const float* __restrict__ wdecb, float* __restrict__ decp) {
  __shared__ float sh[DECn];
  int b = blockIdx.x, d = threadIdx.x;
  float g[4];
#pragma unroll
  for (int gi = 0; gi < 4; gi++) {
    int col = gi * 512 + d;
    float s = bih[col] + bhh[col];
#pragma unroll
    for (int sl = 0; sl < 3; sl++) s += part[((size_t)sl * 64 + b) * 2048 + col];
    g[gi] = s;
  }
  size_t ci = (size_t)b * DECn + d;
  float cn = sigm(g[1]) * cbuf[ci] + sigm(g[0]) * tanh_fast(g[2]);
  float hn = sigm(g[3]) * tanh_fast(cn);
  cbuf[ci] = cn;
  hnew[ci] = f2bf(hn);
  sh[d] = hn;
  __syncthreads();
  // decp[b][d] = sum_k sh[k] * wdecT[k][d]  (coalesced across d)
  float acc = 0.f;
#pragma unroll 8
  for (int k = 0; k < DECn; k++) acc += sh[k] * bf2f(wdecT[(size_t)k * DECn + d]);
  decp[ci] = acc + wdecb[d];
}

// ---------------- deferred logits GEMM: [1280,10000] = Hall @ fcw^T + b -------
__global__ __launch_bounds__(256) void k_logits(
    const u16* __restrict__ hA, const u16* __restrict__ Wbf,
    const float* __restrict__ bias, float* __restrict__ out) {
  __shared__ u16 As[128][32];
  __shared__ u16 Bs[128][32];
  int tid = threadIdx.x;
  int wid = tid >> 6, lane = tid & 63, r = lane & 15, hi = lane >> 4;
  int wm = wid >> 1, wn = wid & 1;
  int m0 = blockIdx.y * 128, n0 = blockIdx.x * 128;
  int srow = tid >> 2, scol = (tid & 3) * 8;
  const u16* ga = hA + (size_t)(m0 + srow) * 512 + scol;
  int br1 = n0 + srow;       if (br1 > VOCABn - 1) br1 = VOCABn - 1;
  int br2 = n0 + 64 + srow;  if (br2 > VOCABn - 1) br2 = VOCABn - 1;
  const u16* gb1 = Wbf + (size_t)br1 * 512 + scol;
  const u16* gb2 = Wbf + (size_t)br2 * 512 + scol;
  u16* As1 = &As[0][0];
  u16* Bs1 = &Bs[0][0];
  f32x4 acc[4][4] = {};
  for (int k0 = 0; k0 < 512; k0 += 32) {
    GLOAD_LDS16(ga + k0,                     As1 + wid * 512);
    GLOAD_LDS16(ga + k0 + (size_t)64 * 512,  As1 + 2048 + wid * 512);
    GLOAD_LDS16(gb1 + k0,                    Bs1 + wid * 512);
    GLOAD_LDS16(gb2 + k0,                    Bs1 + 2048 + wid * 512);
    __syncthreads();
    s16x8 af[4], bfr[4];
#pragma unroll
    for (int i = 0; i < 4; i++) af[i]  = *(const s16x8*)(As1 + (wm * 64 + i * 16 + r) * 32 + hi * 8);
#pragma unroll
    for (int j = 0; j < 4; j++) bfr[j] = *(const s16x8*)(Bs1 + (wn * 64 + j * 16 + r) * 32 + hi * 8);
#pragma unroll
    for (int i = 0; i < 4; i++)
#pragma unroll
      for (int j = 0; j < 4; j++)
        acc[i][j] = mfma(af[i], bfr[j], acc[i][j]);
    __syncthreads();
  }
#pragma unroll
  for (int i = 0; i < 4; i++)
#pragma unroll
    for (int j = 0; j < 4; j++) {
      int col = n0 + wn * 64 + j * 16 + r;
      if (col < VOCABn) {
        float bb = bias[col];
#pragma unroll
        for (int q = 0; q < 4; q++) {
          int row = m0 + wm * 64 + i * 16 + hi * 4 + q;   // row = t*64 + b
          int tt = row >> 6, b = row & 63;
          out[((size_t)b * Sn + tt) * VOCABn + col] = acc[i][j][q] + bb;
        }
      }
    }
}

// ============================================================================
extern "C" void kernel_launch(void* const* d_in, const int* in_sizes, int n_in,
                              void* d_out, int out_size, void* d_ws, size_t ws_size,
                              hipStream_t stream) {
  const float* image_feat = (const float*)d_in[0];
  const int*   captions   = (const int*)d_in[1];
  const float* wenc_w = (const float*)d_in[2];
  const float* wenc_b = (const float*)d_in[3];
  const float* wdec_w = (const float*)d_in[4];
  const float* wdec_b = (const float*)d_in[5];
  const float* V_w    = (const float*)d_in[6];
  const float* V_b    = (const float*)d_in[7];
  const float* embed_w = (const float*)d_in[8];
  const float* h0_w = (const float*)d_in[9];
  const float* h0_b = (const float*)d_in[10];
  const float* c0_w = (const float*)d_in[11];
  const float* c0_b = (const float*)d_in[12];
  const float* W_ih = (const float*)d_in[13];
  const float* b_ih = (const float*)d_in[14];
  const float* W_hh = (const float*)d_in[15];
  const float* b_hh = (const float*)d_in[16];
  const float* fc_w = (const float*)d_in[17];
  const float* fc_b = (const float*)d_in[18];
  float* out = (float*)d_out;

  char* w = (char*)d_ws;
  auto alloc = [&](size_t bytes) { void* p = (void*)w; w += (bytes + 255) & ~(size_t)255; return p; };
  u16* if_bf   = (u16*)alloc(sizeof(u16) * (size_t)Bn * Pn * ENCn);
  u16* wenc_bf = (u16*)alloc(sizeof(u16) * (size_t)ATTn * ENCn);
  u16* wdec_bf = (u16*)alloc(sizeof(u16) * (size_t)ATTn * DECn);
  u16* wdecT   = (u16*)alloc(sizeof(u16) * (size_t)DECn * DECn);
  u16* Wih_bf  = (u16*)alloc(sizeof(u16) * (size_t)2048 * 2560);
  u16* Whh_bf  = (u16*)alloc(sizeof(u16) * (size_t)2048 * 512);
  u16* fcw_bf  = (u16*)alloc(sizeof(u16) * (size_t)VOCABn * DECn);
  u16* hall    = (u16*)alloc(sizeof(u16) * (size_t)(Sn + 1) * Bn * DECn);
  u16* ctx_bf  = (u16*)alloc(sizeof(u16) * (size_t)Bn * ENCn);
  u16* encp    = (u16*)alloc(sizeof(u16) * (size_t)Bn * Pn * ATTn);
  float* avg   = (float*)alloc(sizeof(float) * (size_t)Bn * ENCn);
  float* pavg  = (float*)alloc(sizeof(float) * (size_t)7 * Bn * ENCn);
  float* decp  = (float*)alloc(sizeof(float) * (size_t)Bn * ATTn);
  float* e_s   = (float*)alloc(sizeof(float) * (size_t)Bn * Pn);
  float* cbuf  = (float*)alloc(sizeof(float) * (size_t)Bn * DECn);
  float* part  = (float*)alloc(sizeof(float) * (size_t)3 * Bn * 2048);

  // one-time prep
  k_prep<<<1472, 256, 0, stream>>>(image_feat, if_bf, pavg,
                                   wenc_w, wenc_bf, wdec_w, wdec_bf, wdecT,
                                   W_ih, Wih_bf, W_hh, Whh_bf, fc_w, fcw_bf);
  k_avg_final<<<128, 256, 0, stream>>>(pavg, avg);
  k_encproj<<<dim3(4, 98), 256, 0, stream>>>(if_bf, wenc_bf, wenc_b, encp);
  k_h0c0<<<64, 256, 0, stream>>>(avg, h0_w, h0_b, c0_w, c0_b, hall, cbuf);
  k_lin64<u16, u16, 512><<<32, 256, 0, stream>>>(hall, wdec_bf, wdec_b, decp, 512);

  for (int t = 0; t < Sn; t++) {
    const u16* hin = hall + (size_t)t * Bn * DECn;
    u16* hnew = hall + (size_t)(t + 1) * Bn * DECn;
    k_attn_plus<<<dim3(51, Bn), 256, 0, stream>>>(encp, decp, V_w, V_b, e_s,
                                                  embed_w, captions, t, hin,
                                                  Wih_bf, Whh_bf, part);
    k_ctx<<<dim3(4, Bn), 256, 0, stream>>>(e_s, if_bf, ctx_bf);
    k_gates_ctx<<<dim3(128, 2), 256, 0, stream>>>(ctx_bf, Wih_bf, part);
    k_lstm_decp<<<Bn, 512, 0, stream>>>(part, b_ih, b_hh, cbuf, hnew,
                                        wdecT, wdec_b, decp);
  }
  k_logits<<<dim3(79, 10), 256, 0, stream>>>(hall + (size_t)Bn * DECn, fcw_bf, fc_b, out);
}

// Round 8
// 1112.375 us; speedup vs baseline: 1.3183x; 1.3183x over previous
//
#include <hip/hip_runtime.h>
#include <hip/hip_bf16.h>

#define DEV static __device__ __forceinline__

typedef short s16x8 __attribute__((ext_vector_type(8)));
typedef float f32x4 __attribute__((ext_vector_type(4)));
typedef unsigned short u16;

constexpr int Bn = 64, Pn = 196, ENCn = 2048, EMBn = 512, DECn = 512, ATTn = 512;
constexpr int VOCABn = 10000, Sn = 20;

DEV u16 f2bf(float x) {
  union { float f; unsigned u; } v; v.f = x;
  unsigned r = v.u + 0x7fffu + ((v.u >> 16) & 1u);
  return (u16)(r >> 16);
}
DEV float bf2f(u16 b) {
  union { unsigned u; float f; } v; v.u = ((unsigned)b) << 16;
  return v.f;
}
DEV float sigm(float x) { return 1.f / (1.f + __expf(-x)); }
DEV float tanh_fast(float x) {
  float e = __expf(2.f * x);
  return 1.f - 2.f / (e + 1.f);
}

DEV s16x8 ld8(const u16* p) { return *reinterpret_cast<const s16x8*>(p); }
DEV s16x8 ld8(const float* p) {
  s16x8 r;
#pragma unroll
  for (int j = 0; j < 8; j++) r[j] = (short)f2bf(p[j]);
  return r;
}
DEV f32x4 mfma(s16x8 a, s16x8 b, f32x4 c) {
  return __builtin_amdgcn_mfma_f32_16x16x32_bf16(a, b, c, 0, 0, 0);
}

#define GLOAD_LDS16(gsrc, ldst)                                                \
  __builtin_amdgcn_global_load_lds(                                            \
      (const __attribute__((address_space(1))) void*)(gsrc),                   \
      (__attribute__((address_space(3))) void*)(ldst), 16, 0, 0)

// ---------------- image_feat cvt + partial mean (R6-proven, 448 blocks) -------
__global__ __launch_bounds__(256) void k_cvtfeat_part(
    const float* __restrict__ feat, u16* __restrict__ featbf,
    float* __restrict__ pavg) {
  int b = blockIdx.y, px = blockIdx.x;
  int d8 = threadIdx.x * 8;
  const float* p = feat + ((size_t)b * Pn + px * 28) * ENCn + d8;
  u16* q = featbf + ((size_t)b * Pn + px * 28) * ENCn + d8;
  float acc[8] = {};
  for (int k = 0; k < 28; k++) {
    float4 v0 = *(const float4*)(p + (size_t)k * ENCn);
    float4 v1 = *(const float4*)(p + (size_t)k * ENCn + 4);
    acc[0] += v0.x; acc[1] += v0.y; acc[2] += v0.z; acc[3] += v0.w;
    acc[4] += v1.x; acc[5] += v1.y; acc[6] += v1.z; acc[7] += v1.w;
    s16x8 o;
    o[0] = (short)f2bf(v0.x); o[1] = (short)f2bf(v0.y);
    o[2] = (short)f2bf(v0.z); o[3] = (short)f2bf(v0.w);
    o[4] = (short)f2bf(v1.x); o[5] = (short)f2bf(v1.y);
    o[6] = (short)f2bf(v1.z); o[7] = (short)f2bf(v1.w);
    *(s16x8*)(q + (size_t)k * ENCn) = o;
  }
  float* pp = pavg + ((size_t)px * Bn + b) * ENCn + d8;
  *(f32x4*)pp = f32x4{acc[0], acc[1], acc[2], acc[3]};
  *(f32x4*)(pp + 4) = f32x4{acc[4], acc[5], acc[6], acc[7]};
}

// ---------------- final mean reduce -------------------------------------------
__global__ __launch_bounds__(256) void k_avg_final(
    const float* __restrict__ pavg, float* __restrict__ avg) {
  int idx = blockIdx.x * 256 + threadIdx.x;
  int b = idx >> 9, e4 = (idx & 511) * 4;
  float4 s = {0.f, 0.f, 0.f, 0.f};
#pragma unroll
  for (int px = 0; px < 7; px++) {
    float4 v = *(const float4*)(pavg + ((size_t)px * Bn + b) * ENCn + e4);
    s.x += v.x; s.y += v.y; s.z += v.z; s.w += v.w;
  }
  float4 o = { s.x * (1.f/196.f), s.y * (1.f/196.f), s.z * (1.f/196.f), s.w * (1.f/196.f) };
  *(float4*)(avg + (size_t)b * ENCn + e4) = o;
}

// ---------------- weight conversions (R6-proven) + wdecT ----------------------
__global__ void k_cvt_all(const float* __restrict__ s0, u16* __restrict__ d0,
                          const float* __restrict__ s1, u16* __restrict__ d1,
                          const float* __restrict__ s2, u16* __restrict__ d2,
                          const float* __restrict__ s3, u16* __restrict__ d3,
                          const float* __restrict__ s4, u16* __restrict__ d4,
                          u16* __restrict__ wdecT) {
  int gid = blockIdx.x * 256 + threadIdx.x, stride = gridDim.x * 256;
  auto run = [&](const float* __restrict__ s, u16* __restrict__ d, int n8) {
    for (int i = gid; i < n8; i += stride) {
      const float4* sp = (const float4*)(s + (size_t)i * 8);
      float4 a = sp[0], b = sp[1];
      s16x8 o;
      o[0] = (short)f2bf(a.x); o[1] = (short)f2bf(a.y);
      o[2] = (short)f2bf(a.z); o[3] = (short)f2bf(a.w);
      o[4] = (short)f2bf(b.x); o[5] = (short)f2bf(b.y);
      o[6] = (short)f2bf(b.z); o[7] = (short)f2bf(b.w);
      *(s16x8*)(d + (size_t)i * 8) = o;
    }
  };
  run(s0, d0, 131072);   // wenc 512*2048
  run(s1, d1, 32768);    // wdec 512*512
  run(s2, d2, 655360);   // W_ih 2048*2560
  run(s3, d3, 131072);   // W_hh 2048*512
  run(s4, d4, 640000);   // fc_w 10000*512
  // wdecT[k][n] = wdec[n][k]
  for (int i = gid; i < 262144; i += stride) {
    int n = i >> 9, k = i & 511;
    wdecT[(size_t)k * 512 + n] = f2bf(s1[i]);
  }
}

// ---------------- h0 + c0 (R6) + zero decpart[1..3] ---------------------------
__global__ __launch_bounds__(256) void k_h0c0(
    const float* __restrict__ avg,
    const float* __restrict__ h0w, const float* __restrict__ h0b,
    const float* __restrict__ c0w, const float* __restrict__ c0b,
    u16* __restrict__ h0out, float* __restrict__ c0out,
    float* __restrict__ decpart) {
  int idx = blockIdx.x * 256 + threadIdx.x;   // 16384 threads
  float* dz = decpart + (size_t)Bn * 512;     // slices 1..3 = 98304 floats
#pragma unroll
  for (int j = 0; j < 6; j++) dz[(size_t)j * 16384 + idx] = 0.f;

  int wid = threadIdx.x >> 6, lane = threadIdx.x & 63;
  int r = lane & 15, hi = lane >> 4;
  bool isC = blockIdx.x >= 32;
  int n0 = ((int)blockIdx.x & 31) * 16;
  const float* W = (isC ? c0w : h0w) + (size_t)(n0 + r) * ENCn + hi * 8;
  const float* ap = avg + (size_t)(wid * 16 + r) * ENCn + hi * 8;
  f32x4 acc = {0.f, 0.f, 0.f, 0.f};
  for (int k = 0; k < ENCn; k += 32) acc = mfma(ld8(ap + k), ld8(W + k), acc);
  int col = n0 + r;
  float bb = (isC ? c0b : h0b)[col];
#pragma unroll
  for (int j = 0; j < 4; j++) {
    int row = wid * 16 + hi * 4 + j;
    float v = fmaxf(acc[j] + bb, 0.f);
    if (isC) c0out[(size_t)row * DECn + col] = v;
    else     h0out[(size_t)row * DECn + col] = f2bf(v);
  }
}

// ---------------- generic skinny GEMM (decp0 -> decpart[0], no bias) ----------
template<typename TA, typename TW, int K>
__global__ __launch_bounds__(256) void k_lin64(
    const TA* __restrict__ A, const TW* __restrict__ W,
    const float* __restrict__ bias1, float* __restrict__ outF, size_t ldo) {
  int wid = threadIdx.x >> 6, lane = threadIdx.x & 63;
  int r = lane & 15, hi = lane >> 4;
  int n0 = blockIdx.x * 16;
  const TA* ap = A + (size_t)(wid * 16 + r) * K + hi * 8;
  const TW* wp = W + (size_t)(n0 + r) * K + hi * 8;
  f32x4 acc = {0.f, 0.f, 0.f, 0.f};
  for (int k = 0; k < K; k += 32) acc = mfma(ld8(ap + k), ld8(wp + k), acc);
  int col = n0 + r;
  float bb = bias1 ? bias1[col] : 0.f;
#pragma unroll
  for (int j = 0; j < 4; j++) {
    int row = wid * 16 + hi * 4 + j;
    outF[(size_t)row * ldo + col] = acc[j] + bb;
  }
}

// ---------------- enc_proj (R6-proven) ----------------------------------------
__global__ __launch_bounds__(256) void k_encproj(
    const u16* __restrict__ Abf, const u16* __restrict__ Wbf,
    const float* __restrict__ bias, u16* __restrict__ out) {
  __shared__ u16 As[128][32];
  __shared__ u16 Bs[128][32];
  int tid = threadIdx.x;
  int wid = tid >> 6, lane = tid & 63, r = lane & 15, hi = lane >> 4;
  int wm = wid >> 1, wn = wid & 1;
  int m0 = blockIdx.y * 128, n0 = blockIdx.x * 128;
  int srow = tid >> 2, scol = (tid & 3) * 8;
  const u16* ga = Abf + (size_t)(m0 + srow) * ENCn + scol;
  const u16* gb = Wbf + (size_t)(n0 + srow) * ENCn + scol;
  u16* As1 = &As[0][0];
  u16* Bs1 = &Bs[0][0];
  f32x4 acc[4][4] = {};
  for (int k0 = 0; k0 < ENCn; k0 += 32) {
    GLOAD_LDS16(ga + k0,                      As1 + wid * 512);
    GLOAD_LDS16(ga + k0 + (size_t)64 * ENCn,  As1 + 2048 + wid * 512);
    GLOAD_LDS16(gb + k0,                      Bs1 + wid * 512);
    GLOAD_LDS16(gb + k0 + (size_t)64 * ENCn,  Bs1 + 2048 + wid * 512);
    __syncthreads();
    s16x8 af[4], bfr[4];
#pragma unroll
    for (int i = 0; i < 4; i++) af[i]  = *(const s16x8*)(As1 + (wm * 64 + i * 16 + r) * 32 + hi * 8);
#pragma unroll
    for (int j = 0; j < 4; j++) bfr[j] = *(const s16x8*)(Bs1 + (wn * 64 + j * 16 + r) * 32 + hi * 8);
#pragma unroll
    for (int i = 0; i < 4; i++)
#pragma unroll
      for (int j = 0; j < 4; j++)
        acc[i][j] = mfma(af[i], bfr[j], acc[i][j]);
    __syncthreads();
  }
#pragma unroll
  for (int i = 0; i < 4; i++)
#pragma unroll
    for (int j = 0; j < 4; j++) {
      int col = n0 + wn * 64 + j * 16 + r;
      float bb = bias[col];
#pragma unroll
      for (int q = 0; q < 4; q++) {
        int row = m0 + wm * 64 + i * 16 + hi * 4 + q;
        out[(size_t)row * 512 + col] = f2bf(acc[i][j][q] + bb);
      }
    }
}

// ---------------- G = feat @ Wih_ctx^T, cols gate-interleaved -----------------
// G'[row][d*4+g] = feat[row,:] . Wih[g*512+d, 0:2048].  grid (16, 98).
// Weight-row permutation applied at staging; output writes stay coalesced.
__global__ __launch_bounds__(256) void k_gproj(
    const u16* __restrict__ Abf, const u16* __restrict__ Wih,
    u16* __restrict__ G) {
  __shared__ u16 As[128][32];
  __shared__ u16 Bs[128][32];
  int tid = threadIdx.x;
  int wid = tid >> 6, lane = tid & 63, r = lane & 15, hi = lane >> 4;
  int wm = wid >> 1, wn = wid & 1;
  int m0 = blockIdx.y * 128, n0 = blockIdx.x * 128;
  int srow = tid >> 2, scol = (tid & 3) * 8;
  const u16* ga = Abf + (size_t)(m0 + srow) * ENCn + scol;
  int c1 = n0 + srow, c2 = n0 + 64 + srow;           // G' cols
  int w1 = (c1 >> 2) + (c1 & 3) * 512;               // weight rows (inverse perm)
  int w2 = (c2 >> 2) + (c2 & 3) * 512;
  const u16* gb1 = Wih + (size_t)w1 * 2560 + scol;
  const u16* gb2 = Wih + (size_t)w2 * 2560 + scol;
  u16* As1 = &As[0][0];
  u16* Bs1 = &Bs[0][0];
  f32x4 acc[4][4] = {};
  for (int k0 = 0; k0 < ENCn; k0 += 32) {
    GLOAD_LDS16(ga + k0,                      As1 + wid * 512);
    GLOAD_LDS16(ga + k0 + (size_t)64 * ENCn,  As1 + 2048 + wid * 512);
    GLOAD_LDS16(gb1 + k0,                     Bs1 + wid * 512);
    GLOAD_LDS16(gb2 + k0,                     Bs1 + 2048 + wid * 512);
    __syncthreads();
    s16x8 af[4], bfr[4];
#pragma unroll
    for (int i = 0; i < 4; i++) af[i]  = *(const s16x8*)(As1 + (wm * 64 + i * 16 + r) * 32 + hi * 8);
#pragma unroll
    for (int j = 0; j < 4; j++) bfr[j] = *(const s16x8*)(Bs1 + (wn * 64 + j * 16 + r) * 32 + hi * 8);
#pragma unroll
    for (int i = 0; i < 4; i++)
#pragma unroll
      for (int j = 0; j < 4; j++)
        acc[i][j] = mfma(af[i], bfr[j], acc[i][j]);
    __syncthreads();
  }
#pragma unroll
  for (int i = 0; i < 4; i++)
#pragma unroll
    for (int j = 0; j < 4; j++) {
      int col = n0 + wn * 64 + j * 16 + r;
#pragma unroll
      for (int q = 0; q < 4; q++) {
        int row = m0 + wm * 64 + i * 16 + hi * 4 + q;
        G[(size_t)row * 2048 + col] = f2bf(acc[i][j][q]);
      }
    }
}

// ---------------- STEP K1: attn (decp from partials) + emb/h gate slices ------
// grid (51, 64): bx<49 attn wave per (b,p); bx 49..50 gate slices -> p2.
__global__ __launch_bounds__(256) void k_step1(
    const u16* __restrict__ encp, const float* __restrict__ decpart,
    const float* __restrict__ wdecb,
    const float* __restrict__ Vw, const float* __restrict__ Vb,
    float* __restrict__ e_s,
    const float* __restrict__ embw, const int* __restrict__ caps, int t,
    const u16* __restrict__ hin, const u16* __restrict__ Wih,
    const u16* __restrict__ Whh, float* __restrict__ p2) {
  int bx = blockIdx.x, by = blockIdx.y;
  int wid = threadIdx.x >> 6, lane = threadIdx.x & 63;
  if (bx < 49) {
    int p = bx * 4 + wid, b = by;
    int cb = lane * 8;
    // decp[b][cb..cb+7] = sum_q decpart[q][b][.] + wdecb
    float4 dv0 = *(const float4*)(wdecb + cb);
    float4 dv1 = *(const float4*)(wdecb + cb + 4);
#pragma unroll
    for (int q = 0; q < 4; q++) {
      const float* dq = decpart + ((size_t)q * Bn + b) * 512 + cb;
      float4 v0 = *(const float4*)dq, v1 = *(const float4*)(dq + 4);
      dv0.x += v0.x; dv0.y += v0.y; dv0.z += v0.z; dv0.w += v0.w;
      dv1.x += v1.x; dv1.y += v1.y; dv1.z += v1.z; dv1.w += v1.w;
    }
    float4 vv0 = *(const float4*)(Vw + cb), vv1 = *(const float4*)(Vw + cb + 4);
    s16x8 ev = *(const s16x8*)(encp + (((size_t)(b * Pn + p)) << 9) + cb);
    float s = 0.f;
    s += vv0.x * tanh_fast(bf2f((u16)ev[0]) + dv0.x);
    s += vv0.y * tanh_fast(bf2f((u16)ev[1]) + dv0.y);
    s += vv0.z * tanh_fast(bf2f((u16)ev[2]) + dv0.z);
    s += vv0.w * tanh_fast(bf2f((u16)ev[3]) + dv0.w);
    s += vv1.x * tanh_fast(bf2f((u16)ev[4]) + dv1.x);
    s += vv1.y * tanh_fast(bf2f((u16)ev[5]) + dv1.y);
    s += vv1.z * tanh_fast(bf2f((u16)ev[6]) + dv1.z);
    s += vv1.w * tanh_fast(bf2f((u16)ev[7]) + dv1.w);
    for (int m = 32; m; m >>= 1) s += __shfl_xor(s, m);
    if (lane == 0) e_s[(size_t)b * Pn + p] = s + Vb[0];
  } else {
    int sb = (bx - 49) * 64 + by;          // 0..127
    int n0 = sb * 16;
    int r = lane & 15, hi = lane >> 4;
    int brow = wid * 16 + r;
    f32x4 acc = {0.f, 0.f, 0.f, 0.f};
    int id = caps[brow * Sn + t];
    const float* a = embw + (size_t)id * EMBn + hi * 8;
    const u16* w = Wih + (size_t)(n0 + r) * 2560 + 2048 + hi * 8;
#pragma unroll 4
    for (int k = 0; k < 512; k += 32) acc = mfma(ld8(a + k), ld8(w + k), acc);
    const u16* a2 = hin + (size_t)brow * DECn + hi * 8;
    const u16* w2 = Whh + (size_t)(n0 + r) * 512 + hi * 8;
#pragma unroll 4
    for (int k = 0; k < 512; k += 32) acc = mfma(ld8(a2 + k), ld8(w2 + k), acc);
#pragma unroll
    for (int j = 0; j < 4; j++) {
      int row = wid * 16 + hi * 4 + j;
      p2[(size_t)row * 2048 + n0 + r] = acc[j];
    }
  }
}

// ---------------- STEP K2: softmax + G-weighted-sum + LSTM + decp partials ----
// grid (4, 64): block (chunk c, b) owns LSTM dims d in [c*128, c*128+128).
__global__ __launch_bounds__(256) void k_step2(
    const float* __restrict__ e_s, const u16* __restrict__ G,
    const float* __restrict__ p2, const float* __restrict__ bih,
    const float* __restrict__ bhh, float* __restrict__ cbuf,
    u16* __restrict__ hnew, const u16* __restrict__ wdecT,
    float* __restrict__ decpart) {
  __shared__ float sw[Pn];
  __shared__ float red[256];
  __shared__ float pacc[4 * 512];
  __shared__ float hsh[128];
  int b = blockIdx.y, c = blockIdx.x, tid = threadIdx.x;
  // softmax over 196 (block-wide recompute)
  float ev = (tid < Pn) ? e_s[(size_t)b * Pn + tid] : -3.0e38f;
  red[tid] = ev; __syncthreads();
  for (int s = 128; s > 0; s >>= 1) { if (tid < s) red[tid] = fmaxf(red[tid], red[tid + s]); __syncthreads(); }
  float m = red[0]; __syncthreads();
  float ex = (tid < Pn) ? __expf(ev - m) : 0.f;
  red[tid] = ex; __syncthreads();
  for (int s = 128; s > 0; s >>= 1) { if (tid < s) red[tid] += red[tid + s]; __syncthreads(); }
  float inv = 1.f / red[0];
  if (tid < Pn) sw[tid] = ex * inv;
  __syncthreads();
  // weighted sum of G' slice: group g takes p = g, g+4, ...; thread owns 8 cols
  int g = tid >> 6, t64 = tid & 63;
  int dloc = t64 * 8;
  const u16* gp = G + (size_t)b * Pn * 2048 + c * 512 + dloc;
  float acc[8] = {};
#pragma unroll 4
  for (int p = g; p < Pn; p += 4) {
    float w = sw[p];
    s16x8 v = *(const s16x8*)(gp + (size_t)p * 2048);
#pragma unroll
    for (int j = 0; j < 8; j++) acc[j] += w * bf2f((u16)v[j]);
  }
#pragma unroll
  for (int j = 0; j < 8; j++) pacc[g * 512 + dloc + j] = acc[j];
  __syncthreads();
  // LSTM pointwise for the block's 128 dims (cols interleaved d*4+g)
  if (tid < 128) {
    int d = c * 128 + tid;
    float gv[4];
#pragma unroll
    for (int gg = 0; gg < 4; gg++) {
      int lc = tid * 4 + gg;
      float s = pacc[lc] + pacc[512 + lc] + pacc[1024 + lc] + pacc[1536 + lc];
      int col = gg * 512 + d;
      gv[gg] = s + p2[(size_t)b * 2048 + col] + bih[col] + bhh[col];
    }
    size_t ci = (size_t)b * DECn + d;
    float cn = sigm(gv[1]) * cbuf[ci] + sigm(gv[0]) * tanh_fast(gv[2]);
    float hn = sigm(gv[3]) * tanh_fast(cn);
    cbuf[ci] = cn;
    hnew[ci] = f2bf(hn);
    hsh[tid] = hn;
  }
  __syncthreads();
  // decp partial: K-slice over this block's 128 h dims, all 512 cols
  float a0 = 0.f, a1 = 0.f;
#pragma unroll 8
  for (int k = 0; k < 128; k++) {
    float h = hsh[k];
    const u16* wr = wdecT + (size_t)(c * 128 + k) * 512;
    a0 += h * bf2f(wr[tid]);
    a1 += h * bf2f(wr[tid + 256]);
  }
  decpart[((size_t)c * Bn + b) * 512 + tid] = a0;
  decpart[((size_t)c * Bn + b) * 512 + tid + 256] = a1;
}

// ---------------- deferred logits GEMM (R6-proven) ----------------------------
__global__ __launch_bounds__(256) void k_logits(
    const u16* __restrict__ hA, const u16* __restrict__ Wbf,
    const float* __restrict__ bias, float* __restrict__ out) {
  __shared__ u16 As[128][32];
  __shared__ u16 Bs[128][32];
  int tid = threadIdx.x;
  int wid = tid >> 6, lane = tid & 63, r = lane & 15, hi = lane >> 4;
  int wm = wid >> 1, wn = wid & 1;
  int m0 = blockIdx.y * 128, n0 = blockIdx.x * 128;
  int srow = tid >> 2, scol = (tid & 3) * 8;
  const u16* ga = hA + (size_t)(m0 + srow) * 512 + scol;
  int br1 = n0 + srow;       if (br1 > VOCABn - 1) br1 = VOCABn - 1;
  int br2 = n0 + 64 + srow;  if (br2 > VOCABn - 1) br2 = VOCABn - 1;
  const u16* gb1 = Wbf + (size_t)br1 * 512 + scol;
  const u16* gb2 = Wbf + (size_t)br2 * 512 + scol;
  u16* As1 = &As[0][0];
  u16* Bs1 = &Bs[0][0];
  f32x4 acc[4][4] = {};
  for (int k0 = 0; k0 < 512; k0 += 32) {
    GLOAD_LDS16(ga + k0,                     As1 + wid * 512);
    GLOAD_LDS16(ga + k0 + (size_t)64 * 512,  As1 + 2048 + wid * 512);
    GLOAD_LDS16(gb1 + k0,                    Bs1 + wid * 512);
    GLOAD_LDS16(gb2 + k0,                    Bs1 + 2048 + wid * 512);
    __syncthreads();
    s16x8 af[4], bfr[4];
#pragma unroll
    for (int i = 0; i < 4; i++) af[i]  = *(const s16x8*)(As1 + (wm * 64 + i * 16 + r) * 32 + hi * 8);
#pragma unroll
    for (int j = 0; j < 4; j++) bfr[j] = *(const s16x8*)(Bs1 + (wn * 64 + j * 16 + r) * 32 + hi * 8);
#pragma unroll
    for (int i = 0; i < 4; i++)
#pragma unroll
      for (int j = 0; j < 4; j++)
        acc[i][j] = mfma(af[i], bfr[j], acc[i][j]);
    __syncthreads();
  }
#pragma unroll
  for (int i = 0; i < 4; i++)
#pragma unroll
    for (int j = 0; j < 4; j++) {
      int col = n0 + wn * 64 + j * 16 + r;
      if (col < VOCABn) {
        float bb = bias[col];
#pragma unroll
        for (int q = 0; q < 4; q++) {
          int row = m0 + wm * 64 + i * 16 + hi * 4 + q;   // row = t*64 + b
          int tt = row >> 6, b = row & 63;
          out[((size_t)b * Sn + tt) * VOCABn + col] = acc[i][j][q] + bb;
        }
      }
    }
}

// ============================================================================
extern "C" void kernel_launch(void* const* d_in, const int* in_sizes, int n_in,
                              void* d_out, int out_size, void* d_ws, size_t ws_size,
                              hipStream_t stream) {
  const float* image_feat = (const float*)d_in[0];
  const int*   captions   = (const int*)d_in[1];
  const float* wenc_w = (const float*)d_in[2];
  const float* wenc_b = (const float*)d_in[3];
  const float* wdec_w = (const float*)d_in[4];
  const float* wdec_b = (const float*)d_in[5];
  const float* V_w    = (const float*)d_in[6];
  const float* V_b    = (const float*)d_in[7];
  const float* embed_w = (const float*)d_in[8];
  const float* h0_w = (const float*)d_in[9];
  const float* h0_b = (const float*)d_in[10];
  const float* c0_w = (const float*)d_in[11];
  const float* c0_b = (const float*)d_in[12];
  const float* W_ih = (const float*)d_in[13];
  const float* b_ih = (const float*)d_in[14];
  const float* W_hh = (const float*)d_in[15];
  const float* b_hh = (const float*)d_in[16];
  const float* fc_w = (const float*)d_in[17];
  const float* fc_b = (const float*)d_in[18];
  float* out = (float*)d_out;

  char* w = (char*)d_ws;
  auto alloc = [&](size_t bytes) { void* p = (void*)w; w += (bytes + 255) & ~(size_t)255; return p; };
  u16* if_bf   = (u16*)alloc(sizeof(u16) * (size_t)Bn * Pn * ENCn);
  u16* Gbuf    = (u16*)alloc(sizeof(u16) * (size_t)Bn * Pn * 2048);
  u16* wenc_bf = (u16*)alloc(sizeof(u16) * (size_t)ATTn * ENCn);
  u16* wdec_bf = (u16*)alloc(sizeof(u16) * (size_t)ATTn * DECn);
  u16* wdecT   = (u16*)alloc(sizeof(u16) * (size_t)DECn * DECn);
  u16* Wih_bf  = (u16*)alloc(sizeof(u16) * (size_t)2048 * 2560);
  u16* Whh_bf  = (u16*)alloc(sizeof(u16) * (size_t)2048 * 512);
  u16* fcw_bf  = (u16*)alloc(sizeof(u16) * (size_t)VOCABn * DECn);
  u16* hall    = (u16*)alloc(sizeof(u16) * (size_t)(Sn + 1) * Bn * DECn);
  u16* encp    = (u16*)alloc(sizeof(u16) * (size_t)Bn * Pn * ATTn);
  float* avg   = (float*)alloc(sizeof(float) * (size_t)Bn * ENCn);
  float* pavg  = (float*)alloc(sizeof(float) * (size_t)7 * Bn * ENCn);
  float* e_s   = (float*)alloc(sizeof(float) * (size_t)Bn * Pn);
  float* cbuf  = (float*)alloc(sizeof(float) * (size_t)Bn * DECn);
  float* p2    = (float*)alloc(sizeof(float) * (size_t)Bn * 2048);
  float* decpart = (float*)alloc(sizeof(float) * (size_t)4 * Bn * 512);

  // one-time prep (R6-proven split kernels)
  k_cvtfeat_part<<<dim3(7, Bn), 256, 0, stream>>>(image_feat, if_bf, pavg);
  k_avg_final<<<128, 256, 0, stream>>>(pavg, avg);
  k_cvt_all<<<2048, 256, 0, stream>>>(wenc_w, wenc_bf, wdec_w, wdec_bf,
                                      W_ih, Wih_bf, W_hh, Whh_bf, fc_w, fcw_bf,
                                      wdecT);
  k_encproj<<<dim3(4, 98), 256, 0, stream>>>(if_bf, wenc_bf, wenc_b, encp);
  k_gproj<<<dim3(16, 98), 256, 0, stream>>>(if_bf, Wih_bf, Gbuf);
  k_h0c0<<<64, 256, 0, stream>>>(avg, h0_w, h0_b, c0_w, c0_b, hall, cbuf, decpart);
  k_lin64<u16, u16, 512><<<32, 256, 0, stream>>>(hall, wdec_bf, nullptr, decpart, 512);

  for (int t = 0; t < Sn; t++) {
    const u16* hin = hall + (size_t)t * Bn * DECn;
    u16* hnew = hall + (size_t)(t + 1) * Bn * DECn;
    k_step1<<<dim3(51, Bn), 256, 0, stream>>>(encp, decpart, wdec_b, V_w, V_b, e_s,
                                              embed_w, captions, t, hin,
                                              Wih_bf, Whh_bf, p2);
    k_step2<<<dim3(4, Bn), 256, 0, stream>>>(e_s, Gbuf, p2, b_ih, b_hh, cbuf,
                                             hnew, wdecT, decpart);
  }
  k_logits<<<dim3(79, 10), 256, 0, stream>>>(hall + (size_t)Bn * DECn, fcw_bf, fc_b, out);
}

// Round 9
// 990.181 us; speedup vs baseline: 1.4810x; 1.1234x over previous
//
#include <hip/hip_runtime.h>
#include <hip/hip_bf16.h>

#define DEV static __device__ __forceinline__

typedef short s16x8 __attribute__((ext_vector_type(8)));
typedef float f32x4 __attribute__((ext_vector_type(4)));
typedef unsigned short u16;

constexpr int Bn = 64, Pn = 196, ENCn = 2048, EMBn = 512, DECn = 512, ATTn = 512;
constexpr int VOCABn = 10000, Sn = 20;

DEV u16 f2bf(float x) {
  union { float f; unsigned u; } v; v.f = x;
  unsigned r = v.u + 0x7fffu + ((v.u >> 16) & 1u);
  return (u16)(r >> 16);
}
DEV float bf2f(u16 b) {
  union { unsigned u; float f; } v; v.u = ((unsigned)b) << 16;
  return v.f;
}
DEV float sigm(float x) { return 1.f / (1.f + __expf(-x)); }
DEV float tanh_fast(float x) {
  float e = __expf(2.f * x);
  return 1.f - 2.f / (e + 1.f);
}

DEV s16x8 ld8(const u16* p) { return *reinterpret_cast<const s16x8*>(p); }
DEV f32x4 mfma(s16x8 a, s16x8 b, f32x4 c) {
  return __builtin_amdgcn_mfma_f32_16x16x32_bf16(a, b, c, 0, 0, 0);
}

#define GLOAD_LDS16(gsrc, ldst)                                                \
  __builtin_amdgcn_global_load_lds(                                            \
      (const __attribute__((address_space(1))) void*)(gsrc),                   \
      (__attribute__((address_space(3))) void*)(ldst), 16, 0, 0)

// ---------------- image_feat cvt + partial mean: grid (28, 64), 7 rows/block --
__global__ __launch_bounds__(256) void k_cvtfeat_part(
    const float* __restrict__ feat, u16* __restrict__ featbf,
    float* __restrict__ pavg) {
  int b = blockIdx.y, px = blockIdx.x;     // px 0..27
  int d8 = threadIdx.x * 8;
  const float* p = feat + ((size_t)b * Pn + px * 7) * ENCn + d8;
  u16* q = featbf + ((size_t)b * Pn + px * 7) * ENCn + d8;
  float acc[8] = {};
#pragma unroll
  for (int k = 0; k < 7; k++) {
    float4 v0 = *(const float4*)(p + (size_t)k * ENCn);
    float4 v1 = *(const float4*)(p + (size_t)k * ENCn + 4);
    acc[0] += v0.x; acc[1] += v0.y; acc[2] += v0.z; acc[3] += v0.w;
    acc[4] += v1.x; acc[5] += v1.y; acc[6] += v1.z; acc[7] += v1.w;
    s16x8 o;
    o[0] = (short)f2bf(v0.x); o[1] = (short)f2bf(v0.y);
    o[2] = (short)f2bf(v0.z); o[3] = (short)f2bf(v0.w);
    o[4] = (short)f2bf(v1.x); o[5] = (short)f2bf(v1.y);
    o[6] = (short)f2bf(v1.z); o[7] = (short)f2bf(v1.w);
    *(s16x8*)(q + (size_t)k * ENCn) = o;
  }
  float* pp = pavg + ((size_t)px * Bn + b) * ENCn + d8;
  *(f32x4*)pp = f32x4{acc[0], acc[1], acc[2], acc[3]};
  *(f32x4*)(pp + 4) = f32x4{acc[4], acc[5], acc[6], acc[7]};
}

// ---------------- final mean reduce over 28 partials --------------------------
__global__ __launch_bounds__(256) void k_avg_final(
    const float* __restrict__ pavg, float* __restrict__ avg) {
  int idx = blockIdx.x * 256 + threadIdx.x;   // 32768 float4s
  int b = idx >> 9, e4 = (idx & 511) * 4;
  float4 s = {0.f, 0.f, 0.f, 0.f};
#pragma unroll
  for (int px = 0; px < 28; px++) {
    float4 v = *(const float4*)(pavg + ((size_t)px * Bn + b) * ENCn + e4);
    s.x += v.x; s.y += v.y; s.z += v.z; s.w += v.w;
  }
  float4 o = { s.x * (1.f/196.f), s.y * (1.f/196.f), s.z * (1.f/196.f), s.w * (1.f/196.f) };
  *(float4*)(avg + (size_t)b * ENCn + e4) = o;
}

// ---------------- weight conversions + wdecT + embw ---------------------------
__global__ void k_cvt_all(const float* __restrict__ s0, u16* __restrict__ d0,
                          const float* __restrict__ s1, u16* __restrict__ d1,
                          const float* __restrict__ s2, u16* __restrict__ d2,
                          const float* __restrict__ s3, u16* __restrict__ d3,
                          const float* __restrict__ s4, u16* __restrict__ d4,
                          const float* __restrict__ s5, u16* __restrict__ d5,
                          u16* __restrict__ wdecT) {
  int gid = blockIdx.x * 256 + threadIdx.x, stride = gridDim.x * 256;
  auto run = [&](const float* __restrict__ s, u16* __restrict__ d, int n8) {
    for (int i = gid; i < n8; i += stride) {
      const float4* sp = (const float4*)(s + (size_t)i * 8);
      float4 a = sp[0], b = sp[1];
      s16x8 o;
      o[0] = (short)f2bf(a.x); o[1] = (short)f2bf(a.y);
      o[2] = (short)f2bf(a.z); o[3] = (short)f2bf(a.w);
      o[4] = (short)f2bf(b.x); o[5] = (short)f2bf(b.y);
      o[6] = (short)f2bf(b.z); o[7] = (short)f2bf(b.w);
      *(s16x8*)(d + (size_t)i * 8) = o;
    }
  };
  run(s0, d0, 131072);   // wenc 512*2048
  run(s1, d1, 32768);    // wdec 512*512
  run(s2, d2, 655360);   // W_ih 2048*2560
  run(s3, d3, 131072);   // W_hh 2048*512
  run(s4, d4, 640000);   // fc_w 10000*512
  run(s5, d5, 640000);   // embed_w 10000*512
  for (int i = gid; i < 262144; i += stride) {
    int n = i >> 9, k = i & 511;
    wdecT[(size_t)k * 512 + n] = f2bf(s1[i]);
  }
}

// ---------------- h0 + c0 + zero decpart[1..3] --------------------------------
__global__ __launch_bounds__(256) void k_h0c0(
    const float* __restrict__ avg,
    const float* __restrict__ h0w, const float* __restrict__ h0b,
    const float* __restrict__ c0w, const float* __restrict__ c0b,
    u16* __restrict__ h0out, float* __restrict__ c0out,
    float* __restrict__ decpart) {
  int idx = blockIdx.x * 256 + threadIdx.x;   // 16384 threads
  float* dz = decpart + (size_t)Bn * 512;     // slices 1..3 = 98304 floats
#pragma unroll
  for (int j = 0; j < 6; j++) dz[(size_t)j * 16384 + idx] = 0.f;

  int wid = threadIdx.x >> 6, lane = threadIdx.x & 63;
  int r = lane & 15, hi = lane >> 4;
  bool isC = blockIdx.x >= 32;
  int n0 = ((int)blockIdx.x & 31) * 16;
  const float* W = (isC ? c0w : h0w) + (size_t)(n0 + r) * ENCn + hi * 8;
  const float* ap = avg + (size_t)(wid * 16 + r) * ENCn + hi * 8;
  f32x4 acc = {0.f, 0.f, 0.f, 0.f};
  for (int k = 0; k < ENCn; k += 32) {
    s16x8 af, wf;
#pragma unroll
    for (int j = 0; j < 8; j++) { af[j] = (short)f2bf(ap[k + j]); wf[j] = (short)f2bf(W[k + j]); }
    acc = mfma(af, wf, acc);
  }
  int col = n0 + r;
  float bb = (isC ? c0b : h0b)[col];
#pragma unroll
  for (int j = 0; j < 4; j++) {
    int row = wid * 16 + hi * 4 + j;
    float v = fmaxf(acc[j] + bb, 0.f);
    if (isC) c0out[(size_t)row * DECn + col] = v;
    else     h0out[(size_t)row * DECn + col] = f2bf(v);
  }
}

// ---------------- generic skinny GEMM (decp0 -> decpart[0], no bias) ----------
template<typename TA, typename TW, int K>
__global__ __launch_bounds__(256) void k_lin64(
    const TA* __restrict__ A, const TW* __restrict__ W,
    const float* __restrict__ bias1, float* __restrict__ outF, size_t ldo) {
  int wid = threadIdx.x >> 6, lane = threadIdx.x & 63;
  int r = lane & 15, hi = lane >> 4;
  int n0 = blockIdx.x * 16;
  const TA* ap = A + (size_t)(wid * 16 + r) * K + hi * 8;
  const TW* wp = W + (size_t)(n0 + r) * K + hi * 8;
  f32x4 acc = {0.f, 0.f, 0.f, 0.f};
  for (int k = 0; k < K; k += 32) acc = mfma(ld8(ap + k), ld8(wp + k), acc);
  int col = n0 + r;
  float bb = bias1 ? bias1[col] : 0.f;
#pragma unroll
  for (int j = 0; j < 4; j++) {
    int row = wid * 16 + hi * 4 + j;
    outF[(size_t)row * ldo + col] = acc[j] + bb;
  }
}

// ---------------- fused big projection: G (N=2048, interleaved) + encp (N=512)
// grid (20, 98). XOR-swizzled LDS (slot ^= row&3), both sides.
__global__ __launch_bounds__(256) void k_bigproj(
    const u16* __restrict__ Abf, const u16* __restrict__ Wih,
    const u16* __restrict__ Wenc, const float* __restrict__ encb,
    u16* __restrict__ G, u16* __restrict__ encp) {
  __shared__ u16 As[128][32];
  __shared__ u16 Bs[128][32];
  int tid = threadIdx.x;
  int wid = tid >> 6, lane = tid & 63, r = lane & 15, hi = lane >> 4;
  int wm = wid >> 1, wn = wid & 1;
  int m0 = blockIdx.y * 128;
  bool isG = blockIdx.x < 16;
  int n0 = (isG ? (int)blockIdx.x : (int)blockIdx.x - 16) * 128;
  int srow = tid >> 2;
  int scol = (((tid & 3) ^ (srow & 3))) * 8;   // pre-swizzled source slot
  const u16* ga = Abf + (size_t)(m0 + srow) * ENCn + scol;
  const u16 *gb1, *gb2;
  if (isG) {
    int c1 = n0 + srow, c2 = n0 + 64 + srow;
    int w1 = (c1 >> 2) + (c1 & 3) * 512;
    int w2 = (c2 >> 2) + (c2 & 3) * 512;
    gb1 = Wih + (size_t)w1 * 2560 + scol;
    gb2 = Wih + (size_t)w2 * 2560 + scol;
  } else {
    gb1 = Wenc + (size_t)(n0 + srow) * ENCn + scol;
    gb2 = Wenc + (size_t)(n0 + 64 + srow) * ENCn + scol;
  }
  u16* As1 = &As[0][0];
  u16* Bs1 = &Bs[0][0];
  int sa = (hi ^ (r & 3)) * 8;   // swizzled read slot
  f32x4 acc[4][4] = {};
  for (int k0 = 0; k0 < ENCn; k0 += 32) {
    GLOAD_LDS16(ga + k0,                      As1 + wid * 512);
    GLOAD_LDS16(ga + k0 + (size_t)64 * ENCn,  As1 + 2048 + wid * 512);
    GLOAD_LDS16(gb1 + k0,                     Bs1 + wid * 512);
    GLOAD_LDS16(gb2 + k0,                     Bs1 + 2048 + wid * 512);
    __syncthreads();
    s16x8 af[4], bfr[4];
#pragma unroll
    for (int i = 0; i < 4; i++) af[i]  = *(const s16x8*)(As1 + (wm * 64 + i * 16 + r) * 32 + sa);
#pragma unroll
    for (int j = 0; j < 4; j++) bfr[j] = *(const s16x8*)(Bs1 + (wn * 64 + j * 16 + r) * 32 + sa);
#pragma unroll
    for (int i = 0; i < 4; i++)
#pragma unroll
      for (int j = 0; j < 4; j++)
        acc[i][j] = mfma(af[i], bfr[j], acc[i][j]);
    __syncthreads();
  }
#pragma unroll
  for (int i = 0; i < 4; i++)
#pragma unroll
    for (int j = 0; j < 4; j++) {
      int col = n0 + wn * 64 + j * 16 + r;
#pragma unroll
      for (int q = 0; q < 4; q++) {
        int row = m0 + wm * 64 + i * 16 + hi * 4 + q;
        if (isG) G[(size_t)row * 2048 + col] = f2bf(acc[i][j][q]);
        else     encp[(size_t)row * 512 + col] = f2bf(acc[i][j][q] + encb[col]);
      }
    }
}

// ---------------- E = emb(caps) @ Wih_emb^T for ALL steps: [1280,2048], K=512 -
// grid (16, 10). A rows gathered via caps. Swizzled LDS.
__global__ __launch_bounds__(256) void k_eproj(
    const u16* __restrict__ embbf, const int* __restrict__ caps,
    const u16* __restrict__ Wih, float* __restrict__ E) {
  __shared__ u16 As[128][32];
  __shared__ u16 Bs[128][32];
  int tid = threadIdx.x;
  int wid = tid >> 6, lane = tid & 63, r = lane & 15, hi = lane >> 4;
  int wm = wid >> 1, wn = wid & 1;
  int m0 = blockIdx.y * 128, n0 = blockIdx.x * 128;
  int srow = tid >> 2;
  int scol = (((tid & 3) ^ (srow & 3))) * 8;
  int row1 = m0 + srow, row2 = row1 + 64;
  int id1 = caps[(row1 & 63) * Sn + (row1 >> 6)];
  int id2 = caps[(row2 & 63) * Sn + (row2 >> 6)];
  const u16* ga1 = embbf + (size_t)id1 * 512 + scol;
  const u16* ga2 = embbf + (size_t)id2 * 512 + scol;
  const u16* gb1 = Wih + (size_t)(n0 + srow) * 2560 + 2048 + scol;
  const u16* gb2 = Wih + (size_t)(n0 + 64 + srow) * 2560 + 2048 + scol;
  u16* As1 = &As[0][0];
  u16* Bs1 = &Bs[0][0];
  int sa = (hi ^ (r & 3)) * 8;
  f32x4 acc[4][4] = {};
  for (int k0 = 0; k0 < 512; k0 += 32) {
    GLOAD_LDS16(ga1 + k0, As1 + wid * 512);
    GLOAD_LDS16(ga2 + k0, As1 + 2048 + wid * 512);
    GLOAD_LDS16(gb1 + k0, Bs1 + wid * 512);
    GLOAD_LDS16(gb2 + k0, Bs1 + 2048 + wid * 512);
    __syncthreads();
    s16x8 af[4], bfr[4];
#pragma unroll
    for (int i = 0; i < 4; i++) af[i]  = *(const s16x8*)(As1 + (wm * 64 + i * 16 + r) * 32 + sa);
#pragma unroll
    for (int j = 0; j < 4; j++) bfr[j] = *(const s16x8*)(Bs1 + (wn * 64 + j * 16 + r) * 32 + sa);
#pragma unroll
    for (int i = 0; i < 4; i++)
#pragma unroll
      for (int j = 0; j < 4; j++)
        acc[i][j] = mfma(af[i], bfr[j], acc[i][j]);
    __syncthreads();
  }
#pragma unroll
  for (int i = 0; i < 4; i++)
#pragma unroll
    for (int j = 0; j < 4; j++) {
      int col = n0 + wn * 64 + j * 16 + r;
#pragma unroll
      for (int q = 0; q < 4; q++) {
        int row = m0 + wm * 64 + i * 16 + hi * 4 + q;
        E[(size_t)row * 2048 + col] = acc[i][j][q];
      }
    }
}

// ---------------- STEP K1: attn (decp from partials) + h@Whh slices -----------
// grid (51, 64): bx<49 attn wave per (b,p); bx 49..50 -> p2 (K=512 only).
__global__ __launch_bounds__(256) void k_step1(
    const u16* __restrict__ encp, const float* __restrict__ decpart,
    const float* __restrict__ wdecb,
    const float* __restrict__ Vw, const float* __restrict__ Vb,
    float* __restrict__ e_s,
    const u16* __restrict__ hin, const u16* __restrict__ Whh,
    float* __restrict__ p2) {
  int bx = blockIdx.x, by = blockIdx.y;
  int wid = threadIdx.x >> 6, lane = threadIdx.x & 63;
  if (bx < 49) {
    int p = bx * 4 + wid, b = by;
    int cb = lane * 8;
    float4 dv0 = *(const float4*)(wdecb + cb);
    float4 dv1 = *(const float4*)(wdecb + cb + 4);
#pragma unroll
    for (int q = 0; q < 4; q++) {
      const float* dq = decpart + ((size_t)q * Bn + b) * 512 + cb;
      float4 v0 = *(const float4*)dq, v1 = *(const float4*)(dq + 4);
      dv0.x += v0.x; dv0.y += v0.y; dv0.z += v0.z; dv0.w += v0.w;
      dv1.x += v1.x; dv1.y += v1.y; dv1.z += v1.z; dv1.w += v1.w;
    }
    float4 vv0 = *(const float4*)(Vw + cb), vv1 = *(const float4*)(Vw + cb + 4);
    s16x8 ev = *(const s16x8*)(encp + (((size_t)(b * Pn + p)) << 9) + cb);
    float s = 0.f;
    s += vv0.x * tanh_fast(bf2f((u16)ev[0]) + dv0.x);
    s += vv0.y * tanh_fast(bf2f((u16)ev[1]) + dv0.y);
    s += vv0.z * tanh_fast(bf2f((u16)ev[2]) + dv0.z);
    s += vv0.w * tanh_fast(bf2f((u16)ev[3]) + dv0.w);
    s += vv1.x * tanh_fast(bf2f((u16)ev[4]) + dv1.x);
    s += vv1.y * tanh_fast(bf2f((u16)ev[5]) + dv1.y);
    s += vv1.z * tanh_fast(bf2f((u16)ev[6]) + dv1.z);
    s += vv1.w * tanh_fast(bf2f((u16)ev[7]) + dv1.w);
    for (int m = 32; m; m >>= 1) s += __shfl_xor(s, m);
    if (lane == 0) e_s[(size_t)b * Pn + p] = s + Vb[0];
  } else {
    int sb = (bx - 49) * 64 + by;          // 0..127
    int n0 = sb * 16;
    int r = lane & 15, hi = lane >> 4;
    int brow = wid * 16 + r;
    f32x4 acc = {0.f, 0.f, 0.f, 0.f};
    const u16* a2 = hin + (size_t)brow * DECn + hi * 8;
    const u16* w2 = Whh + (size_t)(n0 + r) * 512 + hi * 8;
#pragma unroll 4
    for (int k = 0; k < 512; k += 32) acc = mfma(ld8(a2 + k), ld8(w2 + k), acc);
#pragma unroll
    for (int j = 0; j < 4; j++) {
      int row = wid * 16 + hi * 4 + j;
      p2[(size_t)row * 2048 + n0 + r] = acc[j];
    }
  }
}

// ---------------- STEP K2: softmax + G-sum + LSTM + decp partials, 512 thr ----
// grid (4, 64): block (chunk c, b) owns LSTM dims [c*128, c*128+128).
__global__ __launch_bounds__(512) void k_step2(
    const float* __restrict__ e_s, const u16* __restrict__ G,
    const float* __restrict__ p2, const float* __restrict__ Et,
    const float* __restrict__ bih, const float* __restrict__ bhh,
    float* __restrict__ cbuf, u16* __restrict__ hnew,
    const u16* __restrict__ wdecT, float* __restrict__ decpart) {
  __shared__ float sw[Pn];
  __shared__ float red[512];
  __shared__ float pacc[8 * 512];
  __shared__ float hsh[128];
  int b = blockIdx.y, c = blockIdx.x, tid = threadIdx.x;
  // softmax over 196
  float ev = (tid < Pn) ? e_s[(size_t)b * Pn + tid] : -3.0e38f;
  red[tid] = ev; __syncthreads();
  for (int s = 256; s > 0; s >>= 1) { if (tid < s) red[tid] = fmaxf(red[tid], red[tid + s]); __syncthreads(); }
  float m = red[0]; __syncthreads();
  float ex = (tid < Pn) ? __expf(ev - m) : 0.f;
  red[tid] = ex; __syncthreads();
  for (int s = 256; s > 0; s >>= 1) { if (tid < s) red[tid] += red[tid + s]; __syncthreads(); }
  float inv = 1.f / red[0];
  if (tid < Pn) sw[tid] = ex * inv;
  __syncthreads();
  // weighted sum: 8 p-groups x 64 threads; thread owns 8 cols
  int g = tid >> 6, t64 = tid & 63;
  int dloc = t64 * 8;
  const u16* gp = G + (size_t)b * Pn * 2048 + c * 512 + dloc;
  float acc[8] = {};
#pragma unroll 2
  for (int p = g; p < Pn; p += 8) {
    float w = sw[p];
    s16x8 v = *(const s16x8*)(gp + (size_t)p * 2048);
#pragma unroll
    for (int j = 0; j < 8; j++) acc[j] += w * bf2f((u16)v[j]);
  }
  // conflict-free interleaved store: value for col (t64*8+j) at [g][j*64+t64]
#pragma unroll
  for (int j = 0; j < 8; j++) pacc[g * 512 + j * 64 + t64] = acc[j];
  __syncthreads();
  // LSTM pointwise for 128 dims (G cols interleaved lc = dloc_local*4+g)
  if (tid < 128) {
    int d = c * 128 + tid;
    float gv[4];
#pragma unroll
    for (int gg = 0; gg < 4; gg++) {
      int lc = tid * 4 + gg;
      int ia = (lc & 7) * 64 + (lc >> 3);
      float s = 0.f;
#pragma unroll
      for (int gr = 0; gr < 8; gr++) s += pacc[gr * 512 + ia];
      int col = gg * 512 + d;
      gv[gg] = s + p2[(size_t)b * 2048 + col] + Et[(size_t)b * 2048 + col]
             + bih[col] + bhh[col];
    }
    size_t ci = (size_t)b * DECn + d;
    float cn = sigm(gv[1]) * cbuf[ci] + sigm(gv[0]) * tanh_fast(gv[2]);
    float hn = sigm(gv[3]) * tanh_fast(cn);
    cbuf[ci] = cn;
    hnew[ci] = f2bf(hn);
    hsh[tid] = hn;
  }
  __syncthreads();
  // decp partial: this block's 128 h dims x 512 cols; thread owns 1 col
  float a0 = 0.f;
#pragma unroll 8
  for (int k = 0; k < 128; k++)
    a0 += hsh[k] * bf2f(wdecT[(size_t)(c * 128 + k) * 512 + tid]);
  decpart[((size_t)c * Bn + b) * 512 + tid] = a0;
}

// ---------------- deferred logits GEMM, swizzled ------------------------------
__global__ __launch_bounds__(256) void k_logits(
    const u16* __restrict__ hA, const u16* __restrict__ Wbf,
    const float* __restrict__ bias, float* __restrict__ out) {
  __shared__ u16 As[128][32];
  __shared__ u16 Bs[128][32];
  int tid = threadIdx.x;
  int wid = tid >> 6, lane = tid & 63, r = lane & 15, hi = lane >> 4;
  int wm = wid >> 1, wn = wid & 1;
  int m0 = blockIdx.y * 128, n0 = blockIdx.x * 128;
  int srow = tid >> 2;
  int scol = (((tid & 3) ^ (srow & 3))) * 8;
  const u16* ga = hA + (size_t)(m0 + srow) * 512 + scol;
  int br1 = n0 + srow;       if (br1 > VOCABn - 1) br1 = VOCABn - 1;
  int br2 = n0 + 64 + srow;  if (br2 > VOCABn - 1) br2 = VOCABn - 1;
  const u16* gb1 = Wbf + (size_t)br1 * 512 + scol;
  const u16* gb2 = Wbf + (size_t)br2 * 512 + scol;
  u16* As1 = &As[0][0];
  u16* Bs1 = &Bs[0][0];
  int sa = (hi ^ (r & 3)) * 8;
  f32x4 acc[4][4] = {};
  for (int k0 = 0; k0 < 512; k0 += 32) {
    GLOAD_LDS16(ga + k0,                     As1 + wid * 512);
    GLOAD_LDS16(ga + k0 + (size_t)64 * 512,  As1 + 2048 + wid * 512);
    GLOAD_LDS16(gb1 + k0,                    Bs1 + wid * 512);
    GLOAD_LDS16(gb2 + k0,                    Bs1 + 2048 + wid * 512);
    __syncthreads();
    s16x8 af[4], bfr[4];
#pragma unroll
    for (int i = 0; i < 4; i++) af[i]  = *(const s16x8*)(As1 + (wm * 64 + i * 16 + r) * 32 + sa);
#pragma unroll
    for (int j = 0; j < 4; j++) bfr[j] = *(const s16x8*)(Bs1 + (wn * 64 + j * 16 + r) * 32 + sa);
#pragma unroll
    for (int i = 0; i < 4; i++)
#pragma unroll
      for (int j = 0; j < 4; j++)
        acc[i][j] = mfma(af[i], bfr[j], acc[i][j]);
    __syncthreads();
  }
#pragma unroll
  for (int i = 0; i < 4; i++)
#pragma unroll
    for (int j = 0; j < 4; j++) {
      int col = n0 + wn * 64 + j * 16 + r;
      if (col < VOCABn) {
        float bb = bias[col];
#pragma unroll
        for (int q = 0; q < 4; q++) {
          int row = m0 + wm * 64 + i * 16 + hi * 4 + q;   // row = t*64 + b
          int tt = row >> 6, b = row & 63;
          out[((size_t)b * Sn + tt) * VOCABn + col] = acc[i][j][q] + bb;
        }
      }
    }
}

// ============================================================================
extern "C" void kernel_launch(void* const* d_in, const int* in_sizes, int n_in,
                              void* d_out, int out_size, void* d_ws, size_t ws_size,
                              hipStream_t stream) {
  const float* image_feat = (const float*)d_in[0];
  const int*   captions   = (const int*)d_in[1];
  const float* wenc_w = (const float*)d_in[2];
  const float* wenc_b = (const float*)d_in[3];
  const float* wdec_w = (const float*)d_in[4];
  const float* wdec_b = (const float*)d_in[5];
  const float* V_w    = (const float*)d_in[6];
  const float* V_b    = (const float*)d_in[7];
  const float* embed_w = (const float*)d_in[8];
  const float* h0_w = (const float*)d_in[9];
  const float* h0_b = (const float*)d_in[10];
  const float* c0_w = (const float*)d_in[11];
  const float* c0_b = (const float*)d_in[12];
  const float* W_ih = (const float*)d_in[13];
  const float* b_ih = (const float*)d_in[14];
  const float* W_hh = (const float*)d_in[15];
  const float* b_hh = (const float*)d_in[16];
  const float* fc_w = (const float*)d_in[17];
  const float* fc_b = (const float*)d_in[18];
  float* out = (float*)d_out;

  char* w = (char*)d_ws;
  auto alloc = [&](size_t bytes) { void* p = (void*)w; w += (bytes + 255) & ~(size_t)255; return p; };
  u16* if_bf   = (u16*)alloc(sizeof(u16) * (size_t)Bn * Pn * ENCn);
  u16* Gbuf    = (u16*)alloc(sizeof(u16) * (size_t)Bn * Pn * 2048);
  u16* wenc_bf = (u16*)alloc(sizeof(u16) * (size_t)ATTn * ENCn);
  u16* wdec_bf = (u16*)alloc(sizeof(u16) * (size_t)ATTn * DECn);
  u16* wdecT   = (u16*)alloc(sizeof(u16) * (size_t)DECn * DECn);
  u16* Wih_bf  = (u16*)alloc(sizeof(u16) * (size_t)2048 * 2560);
  u16* Whh_bf  = (u16*)alloc(sizeof(u16) * (size_t)2048 * 512);
  u16* fcw_bf  = (u16*)alloc(sizeof(u16) * (size_t)VOCABn * DECn);
  u16* emb_bf  = (u16*)alloc(sizeof(u16) * (size_t)VOCABn * EMBn);
  u16* hall    = (u16*)alloc(sizeof(u16) * (size_t)(Sn + 1) * Bn * DECn);
  u16* encp    = (u16*)alloc(sizeof(u16) * (size_t)Bn * Pn * ATTn);
  float* Ebuf  = (float*)alloc(sizeof(float) * (size_t)Sn * Bn * 2048);
  float* avg   = (float*)alloc(sizeof(float) * (size_t)Bn * ENCn);
  float* pavg  = (float*)alloc(sizeof(float) * (size_t)28 * Bn * ENCn);
  float* e_s   = (float*)alloc(sizeof(float) * (size_t)Bn * Pn);
  float* cbuf  = (float*)alloc(sizeof(float) * (size_t)Bn * DECn);
  float* p2    = (float*)alloc(sizeof(float) * (size_t)Bn * 2048);
  float* decpart = (float*)alloc(sizeof(float) * (size_t)4 * Bn * 512);

  // one-time prep
  k_cvtfeat_part<<<dim3(28, Bn), 256, 0, stream>>>(image_feat, if_bf, pavg);
  k_avg_final<<<128, 256, 0, stream>>>(pavg, avg);
  k_cvt_all<<<2048, 256, 0, stream>>>(wenc_w, wenc_bf, wdec_w, wdec_bf,
                                      W_ih, Wih_bf, W_hh, Whh_bf, fc_w, fcw_bf,
                                      embed_w, emb_bf, wdecT);
  k_bigproj<<<dim3(20, 98), 256, 0, stream>>>(if_bf, Wih_bf, wenc_bf, wenc_b,
                                              Gbuf, encp);
  k_eproj<<<dim3(16, 10), 256, 0, stream>>>(emb_bf, captions, Wih_bf, Ebuf);
  k_h0c0<<<64, 256, 0, stream>>>(avg, h0_w, h0_b, c0_w, c0_b, hall, cbuf, decpart);
  k_lin64<u16, u16, 512><<<32, 256, 0, stream>>>(hall, wdec_bf, nullptr, decpart, 512);

  for (int t = 0; t < Sn; t++) {
    const u16* hin = hall + (size_t)t * Bn * DECn;
    u16* hnew = hall + (size_t)(t + 1) * Bn * DECn;
    k_step1<<<dim3(51, Bn), 256, 0, stream>>>(encp, decpart, wdec_b, V_w, V_b, e_s,
                                              hin, Whh_bf, p2);
    k_step2<<<dim3(4, Bn), 512, 0, stream>>>(e_s, Gbuf, p2,
                                             Ebuf + (size_t)t * Bn * 2048,
                                             b_ih, b_hh, cbuf, hnew, wdecT, decpart);
  }
  k_logits<<<dim3(79, 10), 256, 0, stream>>>(hall + (size_t)Bn * DECn, fcw_bf, fc_b, out);
}

// Round 10
// 990.177 us; speedup vs baseline: 1.4810x; 1.0000x over previous
//
#include <hip/hip_runtime.h>
#include <hip/hip_bf16.h>

#define DEV static __device__ __forceinline__

typedef short s16x8 __attribute__((ext_vector_type(8)));
typedef float f32x4 __attribute__((ext_vector_type(4)));
typedef unsigned short u16;

constexpr int Bn = 64, Pn = 196, ENCn = 2048, EMBn = 512, DECn = 512, ATTn = 512;
constexpr int VOCABn = 10000, Sn = 20;

DEV u16 f2bf(float x) {
  union { float f; unsigned u; } v; v.f = x;
  unsigned r = v.u + 0x7fffu + ((v.u >> 16) & 1u);
  return (u16)(r >> 16);
}
DEV float bf2f(u16 b) {
  union { unsigned u; float f; } v; v.u = ((unsigned)b) << 16;
  return v.f;
}
DEV float sigm(float x) { return 1.f / (1.f + __expf(-x)); }
DEV float tanh_fast(float x) {
  float e = __expf(2.f * x);
  return 1.f - 2.f / (e + 1.f);
}

DEV s16x8 ld8(const u16* p) { return *reinterpret_cast<const s16x8*>(p); }
DEV f32x4 mfma(s16x8 a, s16x8 b, f32x4 c) {
  return __builtin_amdgcn_mfma_f32_16x16x32_bf16(a, b, c, 0, 0, 0);
}

#define GLOAD_LDS16(gsrc, ldst)                                                \
  __builtin_amdgcn_global_load_lds(                                            \
      (const __attribute__((address_space(1))) void*)(gsrc),                   \
      (__attribute__((address_space(3))) void*)(ldst), 16, 0, 0)

// ---------------- image_feat cvt + partial mean: grid (28, 64), 7 rows/block --
__global__ __launch_bounds__(256) void k_cvtfeat_part(
    const float* __restrict__ feat, u16* __restrict__ featbf,
    float* __restrict__ pavg) {
  int b = blockIdx.y, px = blockIdx.x;     // px 0..27
  int d8 = threadIdx.x * 8;
  const float* p = feat + ((size_t)b * Pn + px * 7) * ENCn + d8;
  u16* q = featbf + ((size_t)b * Pn + px * 7) * ENCn + d8;
  float acc[8] = {};
#pragma unroll
  for (int k = 0; k < 7; k++) {
    float4 v0 = *(const float4*)(p + (size_t)k * ENCn);
    float4 v1 = *(const float4*)(p + (size_t)k * ENCn + 4);
    acc[0] += v0.x; acc[1] += v0.y; acc[2] += v0.z; acc[3] += v0.w;
    acc[4] += v1.x; acc[5] += v1.y; acc[6] += v1.z; acc[7] += v1.w;
    s16x8 o;
    o[0] = (short)f2bf(v0.x); o[1] = (short)f2bf(v0.y);
    o[2] = (short)f2bf(v0.z); o[3] = (short)f2bf(v0.w);
    o[4] = (short)f2bf(v1.x); o[5] = (short)f2bf(v1.y);
    o[6] = (short)f2bf(v1.z); o[7] = (short)f2bf(v1.w);
    *(s16x8*)(q + (size_t)k * ENCn) = o;
  }
  float* pp = pavg + ((size_t)px * Bn + b) * ENCn + d8;
  *(f32x4*)pp = f32x4{acc[0], acc[1], acc[2], acc[3]};
  *(f32x4*)(pp + 4) = f32x4{acc[4], acc[5], acc[6], acc[7]};
}

// ---------------- weight conversions + wdecT + avg reduce (fused tail) --------
// Runs AFTER k_cvtfeat_part on the same stream, so pavg is complete.
__global__ void k_cvt_all(const float* __restrict__ s0, u16* __restrict__ d0,
                          const float* __restrict__ s1, u16* __restrict__ d1,
                          const float* __restrict__ s2, u16* __restrict__ d2,
                          const float* __restrict__ s3, u16* __restrict__ d3,
                          const float* __restrict__ s4, u16* __restrict__ d4,
                          const float* __restrict__ s5, u16* __restrict__ d5,
                          u16* __restrict__ wdecT,
                          const float* __restrict__ pavg, float* __restrict__ avg) {
  int gid = blockIdx.x * 256 + threadIdx.x, stride = gridDim.x * 256;
  auto run = [&](const float* __restrict__ s, u16* __restrict__ d, int n8) {
    for (int i = gid; i < n8; i += stride) {
      const float4* sp = (const float4*)(s + (size_t)i * 8);
      float4 a = sp[0], b = sp[1];
      s16x8 o;
      o[0] = (short)f2bf(a.x); o[1] = (short)f2bf(a.y);
      o[2] = (short)f2bf(a.z); o[3] = (short)f2bf(a.w);
      o[4] = (short)f2bf(b.x); o[5] = (short)f2bf(b.y);
      o[6] = (short)f2bf(b.z); o[7] = (short)f2bf(b.w);
      *(s16x8*)(d + (size_t)i * 8) = o;
    }
  };
  run(s0, d0, 131072);   // wenc 512*2048
  run(s1, d1, 32768);    // wdec 512*512
  run(s2, d2, 655360);   // W_ih 2048*2560
  run(s3, d3, 131072);   // W_hh 2048*512
  run(s4, d4, 640000);   // fc_w 10000*512
  run(s5, d5, 640000);   // embed_w 10000*512
  for (int i = gid; i < 262144; i += stride) {
    int n = i >> 9, k = i & 511;
    wdecT[(size_t)k * 512 + n] = f2bf(s1[i]);
  }
  // avg = sum(pavg[0..27]) / 196   (32768 float4s)
  for (int i = gid; i < 32768; i += stride) {
    int b = i >> 9, e4 = (i & 511) * 4;
    float4 s = {0.f, 0.f, 0.f, 0.f};
#pragma unroll
    for (int px = 0; px < 28; px++) {
      float4 v = *(const float4*)(pavg + ((size_t)px * Bn + b) * ENCn + e4);
      s.x += v.x; s.y += v.y; s.z += v.z; s.w += v.w;
    }
    float4 o = { s.x * (1.f/196.f), s.y * (1.f/196.f), s.z * (1.f/196.f), s.w * (1.f/196.f) };
    *(float4*)(avg + (size_t)b * ENCn + e4) = o;
  }
}

// ---------------- h0 + c0 + zero decpart[1..3] --------------------------------
__global__ __launch_bounds__(256) void k_h0c0(
    const float* __restrict__ avg,
    const float* __restrict__ h0w, const float* __restrict__ h0b,
    const float* __restrict__ c0w, const float* __restrict__ c0b,
    u16* __restrict__ h0out, float* __restrict__ c0out,
    float* __restrict__ decpart) {
  int idx = blockIdx.x * 256 + threadIdx.x;   // 16384 threads
  float* dz = decpart + (size_t)Bn * 512;     // slices 1..3 = 98304 floats
#pragma unroll
  for (int j = 0; j < 6; j++) dz[(size_t)j * 16384 + idx] = 0.f;

  int wid = threadIdx.x >> 6, lane = threadIdx.x & 63;
  int r = lane & 15, hi = lane >> 4;
  bool isC = blockIdx.x >= 32;
  int n0 = ((int)blockIdx.x & 31) * 16;
  const float* W = (isC ? c0w : h0w) + (size_t)(n0 + r) * ENCn + hi * 8;
  const float* ap = avg + (size_t)(wid * 16 + r) * ENCn + hi * 8;
  f32x4 acc = {0.f, 0.f, 0.f, 0.f};
  for (int k = 0; k < ENCn; k += 32) {
    s16x8 af, wf;
#pragma unroll
    for (int j = 0; j < 8; j++) { af[j] = (short)f2bf(ap[k + j]); wf[j] = (short)f2bf(W[k + j]); }
    acc = mfma(af, wf, acc);
  }
  int col = n0 + r;
  float bb = (isC ? c0b : h0b)[col];
#pragma unroll
  for (int j = 0; j < 4; j++) {
    int row = wid * 16 + hi * 4 + j;
    float v = fmaxf(acc[j] + bb, 0.f);
    if (isC) c0out[(size_t)row * DECn + col] = v;
    else     h0out[(size_t)row * DECn + col] = f2bf(v);
  }
}

// ---------------- generic skinny GEMM (decp0 -> decpart[0], no bias) ----------
template<typename TA, typename TW, int K>
__global__ __launch_bounds__(256) void k_lin64(
    const TA* __restrict__ A, const TW* __restrict__ W,
    const float* __restrict__ bias1, float* __restrict__ outF, size_t ldo) {
  int wid = threadIdx.x >> 6, lane = threadIdx.x & 63;
  int r = lane & 15, hi = lane >> 4;
  int n0 = blockIdx.x * 16;
  const TA* ap = A + (size_t)(wid * 16 + r) * K + hi * 8;
  const TW* wp = W + (size_t)(n0 + r) * K + hi * 8;
  f32x4 acc = {0.f, 0.f, 0.f, 0.f};
  for (int k = 0; k < K; k += 32) acc = mfma(ld8(ap + k), ld8(wp + k), acc);
  int col = n0 + r;
  float bb = bias1 ? bias1[col] : 0.f;
#pragma unroll
  for (int j = 0; j < 4; j++) {
    int row = wid * 16 + hi * 4 + j;
    outF[(size_t)row * ldo + col] = acc[j] + bb;
  }
}

// ---------------- fused big projection: G (N=2048, interleaved) + encp (N=512)
// grid (20, 98). Linear LDS (R8-proven); no swizzle (R9: swizzle was a net loss).
__global__ __launch_bounds__(256) void k_bigproj(
    const u16* __restrict__ Abf, const u16* __restrict__ Wih,
    const u16* __restrict__ Wenc, const float* __restrict__ encb,
    u16* __restrict__ G, u16* __restrict__ encp) {
  __shared__ u16 As[128][32];
  __shared__ u16 Bs[128][32];
  int tid = threadIdx.x;
  int wid = tid >> 6, lane = tid & 63, r = lane & 15, hi = lane >> 4;
  int wm = wid >> 1, wn = wid & 1;
  int m0 = blockIdx.y * 128;
  bool isG = blockIdx.x < 16;
  int n0 = (isG ? (int)blockIdx.x : (int)blockIdx.x - 16) * 128;
  int srow = tid >> 2, scol = (tid & 3) * 8;
  const u16* ga = Abf + (size_t)(m0 + srow) * ENCn + scol;
  const u16 *gb1, *gb2;
  if (isG) {
    int c1 = n0 + srow, c2 = n0 + 64 + srow;
    int w1 = (c1 >> 2) + (c1 & 3) * 512;
    int w2 = (c2 >> 2) + (c2 & 3) * 512;
    gb1 = Wih + (size_t)w1 * 2560 + scol;
    gb2 = Wih + (size_t)w2 * 2560 + scol;
  } else {
    gb1 = Wenc + (size_t)(n0 + srow) * ENCn + scol;
    gb2 = Wenc + (size_t)(n0 + 64 + srow) * ENCn + scol;
  }
  u16* As1 = &As[0][0];
  u16* Bs1 = &Bs[0][0];
  f32x4 acc[4][4] = {};
  for (int k0 = 0; k0 < ENCn; k0 += 32) {
    GLOAD_LDS16(ga + k0,                      As1 + wid * 512);
    GLOAD_LDS16(ga + k0 + (size_t)64 * ENCn,  As1 + 2048 + wid * 512);
    GLOAD_LDS16(gb1 + k0,                     Bs1 + wid * 512);
    GLOAD_LDS16(gb2 + k0,                     Bs1 + 2048 + wid * 512);
    __syncthreads();
    s16x8 af[4], bfr[4];
#pragma unroll
    for (int i = 0; i < 4; i++) af[i]  = *(const s16x8*)(As1 + (wm * 64 + i * 16 + r) * 32 + hi * 8);
#pragma unroll
    for (int j = 0; j < 4; j++) bfr[j] = *(const s16x8*)(Bs1 + (wn * 64 + j * 16 + r) * 32 + hi * 8);
#pragma unroll
    for (int i = 0; i < 4; i++)
#pragma unroll
      for (int j = 0; j < 4; j++)
        acc[i][j] = mfma(af[i], bfr[j], acc[i][j]);
    __syncthreads();
  }
#pragma unroll
  for (int i = 0; i < 4; i++)
#pragma unroll
    for (int j = 0; j < 4; j++) {
      int col = n0 + wn * 64 + j * 16 + r;
#pragma unroll
      for (int q = 0; q < 4; q++) {
        int row = m0 + wm * 64 + i * 16 + hi * 4 + q;
        if (isG) G[(size_t)row * 2048 + col] = f2bf(acc[i][j][q]);
        else     encp[(size_t)row * 512 + col] = f2bf(acc[i][j][q] + encb[col]);
      }
    }
}

// ---------------- E = emb(caps) @ Wih_emb^T for ALL steps: [1280,2048], K=512 -
__global__ __launch_bounds__(256) void k_eproj(
    const u16* __restrict__ embbf, const int* __restrict__ caps,
    const u16* __restrict__ Wih, float* __restrict__ E) {
  __shared__ u16 As[128][32];
  __shared__ u16 Bs[128][32];
  int tid = threadIdx.x;
  int wid = tid >> 6, lane = tid & 63, r = lane & 15, hi = lane >> 4;
  int wm = wid >> 1, wn = wid & 1;
  int m0 = blockIdx.y * 128, n0 = blockIdx.x * 128;
  int srow = tid >> 2, scol = (tid & 3) * 8;
  int row1 = m0 + srow, row2 = row1 + 64;
  int id1 = caps[(row1 & 63) * Sn + (row1 >> 6)];
  int id2 = caps[(row2 & 63) * Sn + (row2 >> 6)];
  const u16* ga1 = embbf + (size_t)id1 * 512 + scol;
  const u16* ga2 = embbf + (size_t)id2 * 512 + scol;
  const u16* gb1 = Wih + (size_t)(n0 + srow) * 2560 + 2048 + scol;
  const u16* gb2 = Wih + (size_t)(n0 + 64 + srow) * 2560 + 2048 + scol;
  u16* As1 = &As[0][0];
  u16* Bs1 = &Bs[0][0];
  f32x4 acc[4][4] = {};
  for (int k0 = 0; k0 < 512; k0 += 32) {
    GLOAD_LDS16(ga1 + k0, As1 + wid * 512);
    GLOAD_LDS16(ga2 + k0, As1 + 2048 + wid * 512);
    GLOAD_LDS16(gb1 + k0, Bs1 + wid * 512);
    GLOAD_LDS16(gb2 + k0, Bs1 + 2048 + wid * 512);
    __syncthreads();
    s16x8 af[4], bfr[4];
#pragma unroll
    for (int i = 0; i < 4; i++) af[i]  = *(const s16x8*)(As1 + (wm * 64 + i * 16 + r) * 32 + hi * 8);
#pragma unroll
    for (int j = 0; j < 4; j++) bfr[j] = *(const s16x8*)(Bs1 + (wn * 64 + j * 16 + r) * 32 + hi * 8);
#pragma unroll
    for (int i = 0; i < 4; i++)
#pragma unroll
      for (int j = 0; j < 4; j++)
        acc[i][j] = mfma(af[i], bfr[j], acc[i][j]);
    __syncthreads();
  }
#pragma unroll
  for (int i = 0; i < 4; i++)
#pragma unroll
    for (int j = 0; j < 4; j++) {
      int col = n0 + wn * 64 + j * 16 + r;
#pragma unroll
      for (int q = 0; q < 4; q++) {
        int row = m0 + wm * 64 + i * 16 + hi * 4 + q;
        E[(size_t)row * 2048 + col] = acc[i][j][q];
      }
    }
}

// ---------------- STEP K1: attn (decp from partials) + h@Whh slices -----------
__global__ __launch_bounds__(256) void k_step1(
    const u16* __restrict__ encp, const float* __restrict__ decpart,
    const float* __restrict__ wdecb,
    const float* __restrict__ Vw, const float* __restrict__ Vb,
    float* __restrict__ e_s,
    const u16* __restrict__ hin, const u16* __restrict__ Whh,
    float* __restrict__ p2) {
  int bx = blockIdx.x, by = blockIdx.y;
  int wid = threadIdx.x >> 6, lane = threadIdx.x & 63;
  if (bx < 49) {
    int p = bx * 4 + wid, b = by;
    int cb = lane * 8;
    float4 dv0 = *(const float4*)(wdecb + cb);
    float4 dv1 = *(const float4*)(wdecb + cb + 4);
#pragma unroll
    for (int q = 0; q < 4; q++) {
      const float* dq = decpart + ((size_t)q * Bn + b) * 512 + cb;
      float4 v0 = *(const float4*)dq, v1 = *(const float4*)(dq + 4);
      dv0.x += v0.x; dv0.y += v0.y; dv0.z += v0.z; dv0.w += v0.w;
      dv1.x += v1.x; dv1.y += v1.y; dv1.z += v1.z; dv1.w += v1.w;
    }
    float4 vv0 = *(const float4*)(Vw + cb), vv1 = *(const float4*)(Vw + cb + 4);
    s16x8 ev = *(const s16x8*)(encp + (((size_t)(b * Pn + p)) << 9) + cb);
    float s = 0.f;
    s += vv0.x * tanh_fast(bf2f((u16)ev[0]) + dv0.x);
    s += vv0.y * tanh_fast(bf2f((u16)ev[1]) + dv0.y);
    s += vv0.z * tanh_fast(bf2f((u16)ev[2]) + dv0.z);
    s += vv0.w * tanh_fast(bf2f((u16)ev[3]) + dv0.w);
    s += vv1.x * tanh_fast(bf2f((u16)ev[4]) + dv1.x);
    s += vv1.y * tanh_fast(bf2f((u16)ev[5]) + dv1.y);
    s += vv1.z * tanh_fast(bf2f((u16)ev[6]) + dv1.z);
    s += vv1.w * tanh_fast(bf2f((u16)ev[7]) + dv1.w);
    for (int m = 32; m; m >>= 1) s += __shfl_xor(s, m);
    if (lane == 0) e_s[(size_t)b * Pn + p] = s + Vb[0];
  } else {
    int sb = (bx - 49) * 64 + by;          // 0..127
    int n0 = sb * 16;
    int r = lane & 15, hi = lane >> 4;
    int brow = wid * 16 + r;
    f32x4 acc = {0.f, 0.f, 0.f, 0.f};
    const u16* a2 = hin + (size_t)brow * DECn + hi * 8;
    const u16* w2 = Whh + (size_t)(n0 + r) * 512 + hi * 8;
#pragma unroll 4
    for (int k = 0; k < 512; k += 32) acc = mfma(ld8(a2 + k), ld8(w2 + k), acc);
#pragma unroll
    for (int j = 0; j < 4; j++) {
      int row = wid * 16 + hi * 4 + j;
      p2[(size_t)row * 2048 + n0 + r] = acc[j];
    }
  }
}

// ---------------- STEP K2: softmax + G-sum + LSTM + decp partials, 512 thr ----
__global__ __launch_bounds__(512) void k_step2(
    const float* __restrict__ e_s, const u16* __restrict__ G,
    const float* __restrict__ p2, const float* __restrict__ Et,
    const float* __restrict__ bih, const float* __restrict__ bhh,
    float* __restrict__ cbuf, u16* __restrict__ hnew,
    const u16* __restrict__ wdecT, float* __restrict__ decpart) {
  __shared__ float sw[Pn];
  __shared__ float red[512];
  __shared__ float pacc[8 * 512];
  __shared__ float hsh[128];
  int b = blockIdx.y, c = blockIdx.x, tid = threadIdx.x;
  // softmax over 196
  float ev = (tid < Pn) ? e_s[(size_t)b * Pn + tid] : -3.0e38f;
  red[tid] = ev; __syncthreads();
  for (int s = 256; s > 0; s >>= 1) { if (tid < s) red[tid] = fmaxf(red[tid], red[tid + s]); __syncthreads(); }
  float m = red[0]; __syncthreads();
  float ex = (tid < Pn) ? __expf(ev - m) : 0.f;
  red[tid] = ex; __syncthreads();
  for (int s = 256; s > 0; s >>= 1) { if (tid < s) red[tid] += red[tid + s]; __syncthreads(); }
  float inv = 1.f / red[0];
  if (tid < Pn) sw[tid] = ex * inv;
  __syncthreads();
  // weighted sum: 8 p-groups x 64 threads; thread owns 8 cols
  int g = tid >> 6, t64 = tid & 63;
  int dloc = t64 * 8;
  const u16* gp = G + (size_t)b * Pn * 2048 + c * 512 + dloc;
  float acc[8] = {};
#pragma unroll 2
  for (int p = g; p < Pn; p += 8) {
    float w = sw[p];
    s16x8 v = *(const s16x8*)(gp + (size_t)p * 2048);
#pragma unroll
    for (int j = 0; j < 8; j++) acc[j] += w * bf2f((u16)v[j]);
  }
#pragma unroll
  for (int j = 0; j < 8; j++) pacc[g * 512 + j * 64 + t64] = acc[j];
  __syncthreads();
  // LSTM pointwise for 128 dims (G cols interleaved lc = d_local*4+g)
  if (tid < 128) {
    int d = c * 128 + tid;
    float gv[4];
#pragma unroll
    for (int gg = 0; gg < 4; gg++) {
      int lc = tid * 4 + gg;
      int ia = (lc & 7) * 64 + (lc >> 3);
      float s = 0.f;
#pragma unroll
      for (int gr = 0; gr < 8; gr++) s += pacc[gr * 512 + ia];
      int col = gg * 512 + d;
      gv[gg] = s + p2[(size_t)b * 2048 + col] + Et[(size_t)b * 2048 + col]
             + bih[col] + bhh[col];
    }
    size_t ci = (size_t)b * DECn + d;
    float cn = sigm(gv[1]) * cbuf[ci] + sigm(gv[0]) * tanh_fast(gv[2]);
    float hn = sigm(gv[3]) * tanh_fast(cn);
    cbuf[ci] = cn;
    hnew[ci] = f2bf(hn);
    hsh[tid] = hn;
  }
  __syncthreads();
  // decp partial: this block's 128 h dims x 512 cols; thread owns 1 col
  float a0 = 0.f;
#pragma unroll 8
  for (int k = 0; k < 128; k++)
    a0 += hsh[k] * bf2f(wdecT[(size_t)(c * 128 + k) * 512 + tid]);
  decpart[((size_t)c * Bn + b) * 512 + tid] = a0;
}

// ---------------- deferred logits GEMM (linear LDS) ---------------------------
__global__ __launch_bounds__(256) void k_logits(
    const u16* __restrict__ hA, const u16* __restrict__ Wbf,
    const float* __restrict__ bias, float* __restrict__ out) {
  __shared__ u16 As[128][32];
  __shared__ u16 Bs[128][32];
  int tid = threadIdx.x;
  int wid = tid >> 6, lane = tid & 63, r = lane & 15, hi = lane >> 4;
  int wm = wid >> 1, wn = wid & 1;
  int m0 = blockIdx.y * 128, n0 = blockIdx.x * 128;
  int srow = tid >> 2, scol = (tid & 3) * 8;
  const u16* ga = hA + (size_t)(m0 + srow) * 512 + scol;
  int br1 = n0 + srow;       if (br1 > VOCABn - 1) br1 = VOCABn - 1;
  int br2 = n0 + 64 + srow;  if (br2 > VOCABn - 1) br2 = VOCABn - 1;
  const u16* gb1 = Wbf + (size_t)br1 * 512 + scol;
  const u16* gb2 = Wbf + (size_t)br2 * 512 + scol;
  u16* As1 = &As[0][0];
  u16* Bs1 = &Bs[0][0];
  f32x4 acc[4][4] = {};
  for (int k0 = 0; k0 < 512; k0 += 32) {
    GLOAD_LDS16(ga + k0,                     As1 + wid * 512);
    GLOAD_LDS16(ga + k0 + (size_t)64 * 512,  As1 + 2048 + wid * 512);
    GLOAD_LDS16(gb1 + k0,                    Bs1 + wid * 512);
    GLOAD_LDS16(gb2 + k0,                    Bs1 + 2048 + wid * 512);
    __syncthreads();
    s16x8 af[4], bfr[4];
#pragma unroll
    for (int i = 0; i < 4; i++) af[i]  = *(const s16x8*)(As1 + (wm * 64 + i * 16 + r) * 32 + hi * 8);
#pragma unroll
    for (int j = 0; j < 4; j++) bfr[j] = *(const s16x8*)(Bs1 + (wn * 64 + j * 16 + r) * 32 + hi * 8);
#pragma unroll
    for (int i = 0; i < 4; i++)
#pragma unroll
      for (int j = 0; j < 4; j++)
        acc[i][j] = mfma(af[i], bfr[j], acc[i][j]);
    __syncthreads();
  }
#pragma unroll
  for (int i = 0; i < 4; i++)
#pragma unroll
    for (int j = 0; j < 4; j++) {
      int col = n0 + wn * 64 + j * 16 + r;
      if (col < VOCABn) {
        float bb = bias[col];
#pragma unroll
        for (int q = 0; q < 4; q++) {
          int row = m0 + wm * 64 + i * 16 + hi * 4 + q;   // row = t*64 + b
          int tt = row >> 6, b = row & 63;
          out[((size_t)b * Sn + tt) * VOCABn + col] = acc[i][j][q] + bb;
        }
      }
    }
}

// ============================================================================
extern "C" void kernel_launch(void* const* d_in, const int* in_sizes, int n_in,
                              void* d_out, int out_size, void* d_ws, size_t ws_size,
                              hipStream_t stream) {
  const float* image_feat = (const float*)d_in[0];
  const int*   captions   = (const int*)d_in[1];
  const float* wenc_w = (const float*)d_in[2];
  const float* wenc_b = (const float*)d_in[3];
  const float* wdec_w = (const float*)d_in[4];
  const float* wdec_b = (const float*)d_in[5];
  const float* V_w    = (const float*)d_in[6];
  const float* V_b    = (const float*)d_in[7];
  const float* embed_w = (const float*)d_in[8];
  const float* h0_w = (const float*)d_in[9];
  const float* h0_b = (const float*)d_in[10];
  const float* c0_w = (const float*)d_in[11];
  const float* c0_b = (const float*)d_in[12];
  const float* W_ih = (const float*)d_in[13];
  const float* b_ih = (const float*)d_in[14];
  const float* W_hh = (const float*)d_in[15];
  const float* b_hh = (const float*)d_in[16];
  const float* fc_w = (const float*)d_in[17];
  const float* fc_b = (const float*)d_in[18];
  float* out = (float*)d_out;

  char* w = (char*)d_ws;
  auto alloc = [&](size_t bytes) { void* p = (void*)w; w += (bytes + 255) & ~(size_t)255; return p; };
  u16* if_bf   = (u16*)alloc(sizeof(u16) * (size_t)Bn * Pn * ENCn);
  u16* Gbuf    = (u16*)alloc(sizeof(u16) * (size_t)Bn * Pn * 2048);
  u16* wenc_bf = (u16*)alloc(sizeof(u16) * (size_t)ATTn * ENCn);
  u16* wdec_bf = (u16*)alloc(sizeof(u16) * (size_t)ATTn * DECn);
  u16* wdecT   = (u16*)alloc(sizeof(u16) * (size_t)DECn * DECn);
  u16* Wih_bf  = (u16*)alloc(sizeof(u16) * (size_t)2048 * 2560);
  u16* Whh_bf  = (u16*)alloc(sizeof(u16) * (size_t)2048 * 512);
  u16* fcw_bf  = (u16*)alloc(sizeof(u16) * (size_t)VOCABn * DECn);
  u16* emb_bf  = (u16*)alloc(sizeof(u16) * (size_t)VOCABn * EMBn);
  u16* hall    = (u16*)alloc(sizeof(u16) * (size_t)(Sn + 1) * Bn * DECn);
  u16* encp    = (u16*)alloc(sizeof(u16) * (size_t)Bn * Pn * ATTn);
  float* Ebuf  = (float*)alloc(sizeof(float) * (size_t)Sn * Bn * 2048);
  float* avg   = (float*)alloc(sizeof(float) * (size_t)Bn * ENCn);
  float* pavg  = (float*)alloc(sizeof(float) * (size_t)28 * Bn * ENCn);
  float* e_s   = (float*)alloc(sizeof(float) * (size_t)Bn * Pn);
  float* cbuf  = (float*)alloc(sizeof(float) * (size_t)Bn * DECn);
  float* p2    = (float*)alloc(sizeof(float) * (size_t)Bn * 2048);
  float* decpart = (float*)alloc(sizeof(float) * (size_t)4 * Bn * 512);

  // one-time prep
  k_cvtfeat_part<<<dim3(28, Bn), 256, 0, stream>>>(image_feat, if_bf, pavg);
  k_cvt_all<<<2048, 256, 0, stream>>>(wenc_w, wenc_bf, wdec_w, wdec_bf,
                                      W_ih, Wih_bf, W_hh, Whh_bf, fc_w, fcw_bf,
                                      embed_w, emb_bf, wdecT, pavg, avg);
  k_bigproj<<<dim3(20, 98), 256, 0, stream>>>(if_bf, Wih_bf, wenc_bf, wenc_b,
                                              Gbuf, encp);
  k_eproj<<<dim3(16, 10), 256, 0, stream>>>(emb_bf, captions, Wih_bf, Ebuf);
  k_h0c0<<<64, 256, 0, stream>>>(avg, h0_w, h0_b, c0_w, c0_b, hall, cbuf, decpart);
  k_lin64<u16, u16, 512><<<32, 256, 0, stream>>>(hall, wdec_bf, nullptr, decpart, 512);

  for (int t = 0; t < Sn; t++) {
    const u16* hin = hall + (size_t)t * Bn * DECn;
    u16* hnew = hall + (size_t)(t + 1) * Bn * DECn;
    k_step1<<<dim3(51, Bn), 256, 0, stream>>>(encp, decpart, wdec_b, V_w, V_b, e_s,
                                              hin, Whh_bf, p2);
    k_step2<<<dim3(4, Bn), 512, 0, stream>>>(e_s, Gbuf, p2,
                                             Ebuf + (size_t)t * Bn * 2048,
                                             b_ih, b_hh, cbuf, hnew, wdecT, decpart);
  }
  k_logits<<<dim3(79, 10), 256, 0, stream>>>(hall + (size_t)Bn * DECn, fcw_bf, fc_b, out);
}

// Round 11
// 979.156 us; speedup vs baseline: 1.4976x; 1.0113x over previous
//
#include <hip/hip_runtime.h>
#include <hip/hip_bf16.h>

#define DEV static __device__ __forceinline__

typedef short s16x8 __attribute__((ext_vector_type(8)));
typedef float f32x4 __attribute__((ext_vector_type(4)));
typedef unsigned short u16;

constexpr int Bn = 64, Pn = 196, ENCn = 2048, EMBn = 512, DECn = 512, ATTn = 512;
constexpr int VOCABn = 10000, Sn = 20;

DEV u16 f2bf(float x) {
  union { float f; unsigned u; } v; v.f = x;
  unsigned r = v.u + 0x7fffu + ((v.u >> 16) & 1u);
  return (u16)(r >> 16);
}
DEV float bf2f(u16 b) {
  union { unsigned u; float f; } v; v.u = ((unsigned)b) << 16;
  return v.f;
}
DEV float sigm(float x) { return 1.f / (1.f + __expf(-x)); }
DEV float tanh_fast(float x) {
  float e = __expf(2.f * x);
  return 1.f - 2.f / (e + 1.f);
}

DEV s16x8 ld8(const u16* p) { return *reinterpret_cast<const s16x8*>(p); }
DEV f32x4 mfma(s16x8 a, s16x8 b, f32x4 c) {
  return __builtin_amdgcn_mfma_f32_16x16x32_bf16(a, b, c, 0, 0, 0);
}

#define GLOAD_LDS16(gsrc, ldst)                                                \
  __builtin_amdgcn_global_load_lds(                                            \
      (const __attribute__((address_space(1))) void*)(gsrc),                   \
      (__attribute__((address_space(3))) void*)(ldst), 16, 0, 0)

// ---------------- image_feat cvt + partial mean: grid (28, 64), 7 rows/block --
__global__ __launch_bounds__(256) void k_cvtfeat_part(
    const float* __restrict__ feat, u16* __restrict__ featbf,
    float* __restrict__ pavg) {
  int b = blockIdx.y, px = blockIdx.x;     // px 0..27
  int d8 = threadIdx.x * 8;
  const float* p = feat + ((size_t)b * Pn + px * 7) * ENCn + d8;
  u16* q = featbf + ((size_t)b * Pn + px * 7) * ENCn + d8;
  float acc[8] = {};
#pragma unroll
  for (int k = 0; k < 7; k++) {
    float4 v0 = *(const float4*)(p + (size_t)k * ENCn);
    float4 v1 = *(const float4*)(p + (size_t)k * ENCn + 4);
    acc[0] += v0.x; acc[1] += v0.y; acc[2] += v0.z; acc[3] += v0.w;
    acc[4] += v1.x; acc[5] += v1.y; acc[6] += v1.z; acc[7] += v1.w;
    s16x8 o;
    o[0] = (short)f2bf(v0.x); o[1] = (short)f2bf(v0.y);
    o[2] = (short)f2bf(v0.z); o[3] = (short)f2bf(v0.w);
    o[4] = (short)f2bf(v1.x); o[5] = (short)f2bf(v1.y);
    o[6] = (short)f2bf(v1.z); o[7] = (short)f2bf(v1.w);
    *(s16x8*)(q + (size_t)k * ENCn) = o;
  }
  float* pp = pavg + ((size_t)px * Bn + b) * ENCn + d8;
  *(f32x4*)pp = f32x4{acc[0], acc[1], acc[2], acc[3]};
  *(f32x4*)(pp + 4) = f32x4{acc[4], acc[5], acc[6], acc[7]};
}

// ---------------- all conversions + W_all pack + wdecT + avg(bf16) -----------
// Runs AFTER k_cvtfeat_part (same stream), so pavg is complete.
__global__ void k_cvt_all(
    const float* __restrict__ wenc, const float* __restrict__ wdec,
    u16* __restrict__ wdec_bf,
    const float* __restrict__ Wih, u16* __restrict__ Wih_bf,
    const float* __restrict__ Whh, u16* __restrict__ Whh_bf,
    const float* __restrict__ fcw, u16* __restrict__ fcw_bf,
    const float* __restrict__ embw, u16* __restrict__ emb_bf,
    const float* __restrict__ h0w, u16* __restrict__ h0w_bf,
    const float* __restrict__ c0w, u16* __restrict__ c0w_bf,
    u16* __restrict__ Wall, u16* __restrict__ wdecT,
    const float* __restrict__ pavg, u16* __restrict__ avgbf) {
  int gid = blockIdx.x * 256 + threadIdx.x, stride = gridDim.x * 256;
  auto run = [&](const float* __restrict__ s, u16* __restrict__ d, int n8) {
    for (int i = gid; i < n8; i += stride) {
      const float4* sp = (const float4*)(s + (size_t)i * 8);
      float4 a = sp[0], b = sp[1];
      s16x8 o;
      o[0] = (short)f2bf(a.x); o[1] = (short)f2bf(a.y);
      o[2] = (short)f2bf(a.z); o[3] = (short)f2bf(a.w);
      o[4] = (short)f2bf(b.x); o[5] = (short)f2bf(b.y);
      o[6] = (short)f2bf(b.z); o[7] = (short)f2bf(b.w);
      *(s16x8*)(d + (size_t)i * 8) = o;
    }
  };
  run(wdec, wdec_bf, 32768);     // 512*512
  run(Wih, Wih_bf, 655360);      // 2048*2560 (eproj uses cols 2048..2559)
  run(Whh, Whh_bf, 131072);      // 2048*512
  run(fcw, fcw_bf, 640000);      // 10000*512
  run(embw, emb_bf, 640000);     // 10000*512
  run(h0w, h0w_bf, 131072);      // 512*2048
  run(c0w, c0w_bf, 131072);      // 512*2048
  // W_all[2560][2048]: rows 0..2047 = Wih[perm(c)][0:2048] (perm = gate
  // interleave, applied HERE so bigproj addressing is branch-free);
  // rows 2048..2559 = wenc rows.
  for (int i = gid; i < 655360; i += stride) {
    int row = i >> 8, k8 = (i & 255) * 8;
    const float* src = (row < 2048)
        ? Wih + (size_t)((row >> 2) + (row & 3) * 512) * 2560 + k8
        : wenc + (size_t)(row - 2048) * 2048 + k8;
    float4 a = *(const float4*)src, b = *(const float4*)(src + 4);
    s16x8 o;
    o[0] = (short)f2bf(a.x); o[1] = (short)f2bf(a.y);
    o[2] = (short)f2bf(a.z); o[3] = (short)f2bf(a.w);
    o[4] = (short)f2bf(b.x); o[5] = (short)f2bf(b.y);
    o[6] = (short)f2bf(b.z); o[7] = (short)f2bf(b.w);
    *(s16x8*)(Wall + (size_t)i * 8) = o;
  }
  // wdecT[k][n] = wdec[n][k]
  for (int i = gid; i < 262144; i += stride) {
    int n = i >> 9, k = i & 511;
    wdecT[(size_t)k * 512 + n] = f2bf(wdec[i]);
  }
  // avgbf = bf16( sum(pavg[0..27]) / 196 )
  for (int i = gid; i < 16384; i += stride) {
    int b = i >> 8, e8 = (i & 255) * 8;
    float s[8] = {};
#pragma unroll 4
    for (int px = 0; px < 28; px++) {
      const float* pp = pavg + ((size_t)px * Bn + b) * ENCn + e8;
      float4 v0 = *(const float4*)pp, v1 = *(const float4*)(pp + 4);
      s[0] += v0.x; s[1] += v0.y; s[2] += v0.z; s[3] += v0.w;
      s[4] += v1.x; s[5] += v1.y; s[6] += v1.z; s[7] += v1.w;
    }
    s16x8 o;
#pragma unroll
    for (int j = 0; j < 8; j++) o[j] = (short)f2bf(s[j] * (1.f / 196.f));
    *(s16x8*)(avgbf + (size_t)b * ENCn + e8) = o;
  }
}

// ---------------- h0 + c0 (bf16 inputs, clean MFMA) + zero decpart[1..3] ------
__global__ __launch_bounds__(256) void k_h0c0(
    const u16* __restrict__ avgbf,
    const u16* __restrict__ h0wbf, const float* __restrict__ h0b,
    const u16* __restrict__ c0wbf, const float* __restrict__ c0b,
    u16* __restrict__ h0out, float* __restrict__ c0out,
    float* __restrict__ decpart) {
  int idx = blockIdx.x * 256 + threadIdx.x;   // 16384 threads
  float* dz = decpart + (size_t)Bn * 512;     // slices 1..3 = 98304 floats
#pragma unroll
  for (int j = 0; j < 6; j++) dz[(size_t)j * 16384 + idx] = 0.f;

  int wid = threadIdx.x >> 6, lane = threadIdx.x & 63;
  int r = lane & 15, hi = lane >> 4;
  bool isC = blockIdx.x >= 32;
  int n0 = ((int)blockIdx.x & 31) * 16;
  const u16* W = (isC ? c0wbf : h0wbf) + (size_t)(n0 + r) * ENCn + hi * 8;
  const u16* ap = avgbf + (size_t)(wid * 16 + r) * ENCn + hi * 8;
  f32x4 acc = {0.f, 0.f, 0.f, 0.f};
#pragma unroll 4
  for (int k = 0; k < ENCn; k += 32) acc = mfma(ld8(ap + k), ld8(W + k), acc);
  int col = n0 + r;
  float bb = (isC ? c0b : h0b)[col];
#pragma unroll
  for (int j = 0; j < 4; j++) {
    int row = wid * 16 + hi * 4 + j;
    float v = fmaxf(acc[j] + bb, 0.f);
    if (isC) c0out[(size_t)row * DECn + col] = v;
    else     h0out[(size_t)row * DECn + col] = f2bf(v);
  }
}

// ---------------- generic skinny GEMM (decp0 -> decpart[0], no bias) ----------
template<typename TA, typename TW, int K>
__global__ __launch_bounds__(256) void k_lin64(
    const TA* __restrict__ A, const TW* __restrict__ W,
    const float* __restrict__ bias1, float* __restrict__ outF, size_t ldo) {
  int wid = threadIdx.x >> 6, lane = threadIdx.x & 63;
  int r = lane & 15, hi = lane >> 4;
  int n0 = blockIdx.x * 16;
  const TA* ap = A + (size_t)(wid * 16 + r) * K + hi * 8;
  const TW* wp = W + (size_t)(n0 + r) * K + hi * 8;
  f32x4 acc = {0.f, 0.f, 0.f, 0.f};
  for (int k = 0; k < K; k += 32) acc = mfma(ld8(ap + k), ld8(wp + k), acc);
  int col = n0 + r;
  float bb = bias1 ? bias1[col] : 0.f;
#pragma unroll
  for (int j = 0; j < 4; j++) {
    int row = wid * 16 + hi * 4 + j;
    outF[(size_t)row * ldo + col] = acc[j] + bb;
  }
}

// ---------------- big projection, branch-free: [12544,2560] = feat @ W_all^T --
// grid (20, 98). cols 0..2047 -> G (gate-interleaved), 2048..2559 -> encp+bias.
__global__ __launch_bounds__(256) void k_bigproj(
    const u16* __restrict__ Abf, const u16* __restrict__ Wall,
    const float* __restrict__ encb,
    u16* __restrict__ G, u16* __restrict__ encp) {
  __shared__ u16 As[128][32];
  __shared__ u16 Bs[128][32];
  int tid = threadIdx.x;
  int wid = tid >> 6, lane = tid & 63, r = lane & 15, hi = lane >> 4;
  int wm = wid >> 1, wn = wid & 1;
  int m0 = blockIdx.y * 128, n0 = blockIdx.x * 128;
  int srow = tid >> 2, scol = (tid & 3) * 8;
  const u16* ga  = Abf  + (size_t)(m0 + srow) * ENCn + scol;
  const u16* gb1 = Wall + (size_t)(n0 + srow) * 2048 + scol;
  const u16* gb2 = Wall + (size_t)(n0 + 64 + srow) * 2048 + scol;
  u16* As1 = &As[0][0];
  u16* Bs1 = &Bs[0][0];
  f32x4 acc[4][4] = {};
  for (int k0 = 0; k0 < ENCn; k0 += 32) {
    GLOAD_LDS16(ga + k0,                      As1 + wid * 512);
    GLOAD_LDS16(ga + k0 + (size_t)64 * ENCn,  As1 + 2048 + wid * 512);
    GLOAD_LDS16(gb1 + k0,                     Bs1 + wid * 512);
    GLOAD_LDS16(gb2 + k0,                     Bs1 + 2048 + wid * 512);
    __syncthreads();
    s16x8 af[4], bfr[4];
#pragma unroll
    for (int i = 0; i < 4; i++) af[i]  = *(const s16x8*)(As1 + (wm * 64 + i * 16 + r) * 32 + hi * 8);
#pragma unroll
    for (int j = 0; j < 4; j++) bfr[j] = *(const s16x8*)(Bs1 + (wn * 64 + j * 16 + r) * 32 + hi * 8);
#pragma unroll
    for (int i = 0; i < 4; i++)
#pragma unroll
      for (int j = 0; j < 4; j++)
        acc[i][j] = mfma(af[i], bfr[j], acc[i][j]);
    __syncthreads();
  }
#pragma unroll
  for (int i = 0; i < 4; i++)
#pragma unroll
    for (int j = 0; j < 4; j++) {
      int col = n0 + wn * 64 + j * 16 + r;
#pragma unroll
      for (int q = 0; q < 4; q++) {
        int row = m0 + wm * 64 + i * 16 + hi * 4 + q;
        if (col < 2048) G[(size_t)row * 2048 + col] = f2bf(acc[i][j][q]);
        else encp[(size_t)row * 512 + (col - 2048)] = f2bf(acc[i][j][q] + encb[col - 2048]);
      }
    }
}

// ---------------- E = emb(caps) @ Wih_emb^T for ALL steps: [1280,2048], K=512 -
__global__ __launch_bounds__(256) void k_eproj(
    const u16* __restrict__ embbf, const int* __restrict__ caps,
    const u16* __restrict__ Wih, float* __restrict__ E) {
  __shared__ u16 As[128][32];
  __shared__ u16 Bs[128][32];
  int tid = threadIdx.x;
  int wid = tid >> 6, lane = tid & 63, r = lane & 15, hi = lane >> 4;
  int wm = wid >> 1, wn = wid & 1;
  int m0 = blockIdx.y * 128, n0 = blockIdx.x * 128;
  int srow = tid >> 2, scol = (tid & 3) * 8;
  int row1 = m0 + srow, row2 = row1 + 64;
  int id1 = caps[(row1 & 63) * Sn + (row1 >> 6)];
  int id2 = caps[(row2 & 63) * Sn + (row2 >> 6)];
  const u16* ga1 = embbf + (size_t)id1 * 512 + scol;
  const u16* ga2 = embbf + (size_t)id2 * 512 + scol;
  const u16* gb1 = Wih + (size_t)(n0 + srow) * 2560 + 2048 + scol;
  const u16* gb2 = Wih + (size_t)(n0 + 64 + srow) * 2560 + 2048 + scol;
  u16* As1 = &As[0][0];
  u16* Bs1 = &Bs[0][0];
  f32x4 acc[4][4] = {};
  for (int k0 = 0; k0 < 512; k0 += 32) {
    GLOAD_LDS16(ga1 + k0, As1 + wid * 512);
    GLOAD_LDS16(ga2 + k0, As1 + 2048 + wid * 512);
    GLOAD_LDS16(gb1 + k0, Bs1 + wid * 512);
    GLOAD_LDS16(gb2 + k0, Bs1 + 2048 + wid * 512);
    __syncthreads();
    s16x8 af[4], bfr[4];
#pragma unroll
    for (int i = 0; i < 4; i++) af[i]  = *(const s16x8*)(As1 + (wm * 64 + i * 16 + r) * 32 + hi * 8);
#pragma unroll
    for (int j = 0; j < 4; j++) bfr[j] = *(const s16x8*)(Bs1 + (wn * 64 + j * 16 + r) * 32 + hi * 8);
#pragma unroll
    for (int i = 0; i < 4; i++)
#pragma unroll
      for (int j = 0; j < 4; j++)
        acc[i][j] = mfma(af[i], bfr[j], acc[i][j]);
    __syncthreads();
  }
#pragma unroll
  for (int i = 0; i < 4; i++)
#pragma unroll
    for (int j = 0; j < 4; j++) {
      int col = n0 + wn * 64 + j * 16 + r;
#pragma unroll
      for (int q = 0; q < 4; q++) {
        int row = m0 + wm * 64 + i * 16 + hi * 4 + q;
        E[(size_t)row * 2048 + col] = acc[i][j][q];
      }
    }
}

// ---------------- STEP K1: attn (decp from partials) + h@Whh slices -----------
__global__ __launch_bounds__(256) void k_step1(
    const u16* __restrict__ encp, const float* __restrict__ decpart,
    const float* __restrict__ wdecb,
    const float* __restrict__ Vw, const float* __restrict__ Vb,
    float* __restrict__ e_s,
    const u16* __restrict__ hin, const u16* __restrict__ Whh,
    float* __restrict__ p2) {
  int bx = blockIdx.x, by = blockIdx.y;
  int wid = threadIdx.x >> 6, lane = threadIdx.x & 63;
  if (bx < 49) {
    int p = bx * 4 + wid, b = by;
    int cb = lane * 8;
    float4 dv0 = *(const float4*)(wdecb + cb);
    float4 dv1 = *(const float4*)(wdecb + cb + 4);
#pragma unroll
    for (int q = 0; q < 4; q++) {
      const float* dq = decpart + ((size_t)q * Bn + b) * 512 + cb;
      float4 v0 = *(const float4*)dq, v1 = *(const float4*)(dq + 4);
      dv0.x += v0.x; dv0.y += v0.y; dv0.z += v0.z; dv0.w += v0.w;
      dv1.x += v1.x; dv1.y += v1.y; dv1.z += v1.z; dv1.w += v1.w;
    }
    float4 vv0 = *(const float4*)(Vw + cb), vv1 = *(const float4*)(Vw + cb + 4);
    s16x8 ev = *(const s16x8*)(encp + (((size_t)(b * Pn + p)) << 9) + cb);
    float s = 0.f;
    s += vv0.x * tanh_fast(bf2f((u16)ev[0]) + dv0.x);
    s += vv0.y * tanh_fast(bf2f((u16)ev[1]) + dv0.y);
    s += vv0.z * tanh_fast(bf2f((u16)ev[2]) + dv0.z);
    s += vv0.w * tanh_fast(bf2f((u16)ev[3]) + dv0.w);
    s += vv1.x * tanh_fast(bf2f((u16)ev[4]) + dv1.x);
    s += vv1.y * tanh_fast(bf2f((u16)ev[5]) + dv1.y);
    s += vv1.z * tanh_fast(bf2f((u16)ev[6]) + dv1.z);
    s += vv1.w * tanh_fast(bf2f((u16)ev[7]) + dv1.w);
    for (int m = 32; m; m >>= 1) s += __shfl_xor(s, m);
    if (lane == 0) e_s[(size_t)b * Pn + p] = s + Vb[0];
  } else {
    int sb = (bx - 49) * 64 + by;          // 0..127
    int n0 = sb * 16;
    int r = lane & 15, hi = lane >> 4;
    int brow = wid * 16 + r;
    f32x4 acc = {0.f, 0.f, 0.f, 0.f};
    const u16* a2 = hin + (size_t)brow * DECn + hi * 8;
    const u16* w2 = Whh + (size_t)(n0 + r) * 512 + hi * 8;
#pragma unroll 4
    for (int k = 0; k < 512; k += 32) acc = mfma(ld8(a2 + k), ld8(w2 + k), acc);
#pragma unroll
    for (int j = 0; j < 4; j++) {
      int row = wid * 16 + hi * 4 + j;
      p2[(size_t)row * 2048 + n0 + r] = acc[j];
    }
  }
}

// ---------------- STEP K2: softmax + G-sum + LSTM + decp partials, 512 thr ----
__global__ __launch_bounds__(512) void k_step2(
    const float* __restrict__ e_s, const u16* __restrict__ G,
    const float* __restrict__ p2, const float* __restrict__ Et,
    const float* __restrict__ bih, const float* __restrict__ bhh,
    float* __restrict__ cbuf, u16* __restrict__ hnew,
    const u16* __restrict__ wdecT, float* __restrict__ decpart) {
  __shared__ float sw[Pn];
  __shared__ float red[512];
  __shared__ float pacc[8 * 512];
  __shared__ float hsh[128];
  int b = blockIdx.y, c = blockIdx.x, tid = threadIdx.x;
  // softmax over 196
  float ev = (tid < Pn) ? e_s[(size_t)b * Pn + tid] : -3.0e38f;
  red[tid] = ev; __syncthreads();
  for (int s = 256; s > 0; s >>= 1) { if (tid < s) red[tid] = fmaxf(red[tid], red[tid + s]); __syncthreads(); }
  float m = red[0]; __syncthreads();
  float ex = (tid < Pn) ? __expf(ev - m) : 0.f;
  red[tid] = ex; __syncthreads();
  for (int s = 256; s > 0; s >>= 1) { if (tid < s) red[tid] += red[tid + s]; __syncthreads(); }
  float inv = 1.f / red[0];
  if (tid < Pn) sw[tid] = ex * inv;
  __syncthreads();
  // weighted sum: 8 p-groups x 64 threads; thread owns 8 cols
  int g = tid >> 6, t64 = tid & 63;
  int dloc = t64 * 8;
  const u16* gp = G + (size_t)b * Pn * 2048 + c * 512 + dloc;
  float acc[8] = {};
#pragma unroll 2
  for (int p = g; p < Pn; p += 8) {
    float w = sw[p];
    s16x8 v = *(const s16x8*)(gp + (size_t)p * 2048);
#pragma unroll
    for (int j = 0; j < 8; j++) acc[j] += w * bf2f((u16)v[j]);
  }
#pragma unroll
  for (int j = 0; j < 8; j++) pacc[g * 512 + j * 64 + t64] = acc[j];
  __syncthreads();
  // LSTM pointwise for 128 dims (G cols interleaved lc = d_local*4+g)
  if (tid < 128) {
    int d = c * 128 + tid;
    float gv[4];
#pragma unroll
    for (int gg = 0; gg < 4; gg++) {
      int lc = tid * 4 + gg;
      int ia = (lc & 7) * 64 + (lc >> 3);
      float s = 0.f;
#pragma unroll
      for (int gr = 0; gr < 8; gr++) s += pacc[gr * 512 + ia];
      int col = gg * 512 + d;
      gv[gg] = s + p2[(size_t)b * 2048 + col] + Et[(size_t)b * 2048 + col]
             + bih[col] + bhh[col];
    }
    size_t ci = (size_t)b * DECn + d;
    float cn = sigm(gv[1]) * cbuf[ci] + sigm(gv[0]) * tanh_fast(gv[2]);
    float hn = sigm(gv[3]) * tanh_fast(cn);
    cbuf[ci] = cn;
    hnew[ci] = f2bf(hn);
    hsh[tid] = hn;
  }
  __syncthreads();
  // decp partial: this block's 128 h dims x 512 cols; thread owns 1 col
  float a0 = 0.f;
#pragma unroll 8
  for (int k = 0; k < 128; k++)
    a0 += hsh[k] * bf2f(wdecT[(size_t)(c * 128 + k) * 512 + tid]);
  decpart[((size_t)c * Bn + b) * 512 + tid] = a0;
}

// ---------------- deferred logits GEMM (linear LDS) ---------------------------
__global__ __launch_bounds__(256) void k_logits(
    const u16* __restrict__ hA, const u16* __restrict__ Wbf,
    const float* __restrict__ bias, float* __restrict__ out) {
  __shared__ u16 As[128][32];
  __shared__ u16 Bs[128][32];
  int tid = threadIdx.x;
  int wid = tid >> 6, lane = tid & 63, r = lane & 15, hi = lane >> 4;
  int wm = wid >> 1, wn = wid & 1;
  int m0 = blockIdx.y * 128, n0 = blockIdx.x * 128;
  int srow = tid >> 2, scol = (tid & 3) * 8;
  const u16* ga = hA + (size_t)(m0 + srow) * 512 + scol;
  int br1 = n0 + srow;       if (br1 > VOCABn - 1) br1 = VOCABn - 1;
  int br2 = n0 + 64 + srow;  if (br2 > VOCABn - 1) br2 = VOCABn - 1;
  const u16* gb1 = Wbf + (size_t)br1 * 512 + scol;
  const u16* gb2 = Wbf + (size_t)br2 * 512 + scol;
  u16* As1 = &As[0][0];
  u16* Bs1 = &Bs[0][0];
  f32x4 acc[4][4] = {};
  for (int k0 = 0; k0 < 512; k0 += 32) {
    GLOAD_LDS16(ga + k0,                     As1 + wid * 512);
    GLOAD_LDS16(ga + k0 + (size_t)64 * 512,  As1 + 2048 + wid * 512);
    GLOAD_LDS16(gb1 + k0,                    Bs1 + wid * 512);
    GLOAD_LDS16(gb2 + k0,                    Bs1 + 2048 + wid * 512);
    __syncthreads();
    s16x8 af[4], bfr[4];
#pragma unroll
    for (int i = 0; i < 4; i++) af[i]  = *(const s16x8*)(As1 + (wm * 64 + i * 16 + r) * 32 + hi * 8);
#pragma unroll
    for (int j = 0; j < 4; j++) bfr[j] = *(const s16x8*)(Bs1 + (wn * 64 + j * 16 + r) * 32 + hi * 8);
#pragma unroll
    for (int i = 0; i < 4; i++)
#pragma unroll
      for (int j = 0; j < 4; j++)
        acc[i][j] = mfma(af[i], bfr[j], acc[i][j]);
    __syncthreads();
  }
#pragma unroll
  for (int i = 0; i < 4; i++)
#pragma unroll
    for (int j = 0; j < 4; j++) {
      int col = n0 + wn * 64 + j * 16 + r;
      if (col < VOCABn) {
        float bb = bias[col];
#pragma unroll
        for (int q = 0; q < 4; q++) {
          int row = m0 + wm * 64 + i * 16 + hi * 4 + q;   // row = t*64 + b
          int tt = row >> 6, b = row & 63;
          out[((size_t)b * Sn + tt) * VOCABn + col] = acc[i][j][q] + bb;
        }
      }
    }
}

// ============================================================================
extern "C" void kernel_launch(void* const* d_in, const int* in_sizes, int n_in,
                              void* d_out, int out_size, void* d_ws, size_t ws_size,
                              hipStream_t stream) {
  const float* image_feat = (const float*)d_in[0];
  const int*   captions   = (const int*)d_in[1];
  const float* wenc_w = (const float*)d_in[2];
  const float* wenc_b = (const float*)d_in[3];
  const float* wdec_w = (const float*)d_in[4];
  const float* wdec_b = (const float*)d_in[5];
  const float* V_w    = (const float*)d_in[6];
  const float* V_b    = (const float*)d_in[7];
  const float* embed_w = (const float*)d_in[8];
  const float* h0_w = (const float*)d_in[9];
  const float* h0_b = (const float*)d_in[10];
  const float* c0_w = (const float*)d_in[11];
  const float* c0_b = (const float*)d_in[12];
  const float* W_ih = (const float*)d_in[13];
  const float* b_ih = (const float*)d_in[14];
  const float* W_hh = (const float*)d_in[15];
  const float* b_hh = (const float*)d_in[16];
  const float* fc_w = (const float*)d_in[17];
  const float* fc_b = (const float*)d_in[18];
  float* out = (float*)d_out;

  char* w = (char*)d_ws;
  auto alloc = [&](size_t bytes) { void* p = (void*)w; w += (bytes + 255) & ~(size_t)255; return p; };
  u16* if_bf   = (u16*)alloc(sizeof(u16) * (size_t)Bn * Pn * ENCn);
  u16* Gbuf    = (u16*)alloc(sizeof(u16) * (size_t)Bn * Pn * 2048);
  u16* Wall    = (u16*)alloc(sizeof(u16) * (size_t)2560 * 2048);
  u16* wdec_bf = (u16*)alloc(sizeof(u16) * (size_t)ATTn * DECn);
  u16* wdecT   = (u16*)alloc(sizeof(u16) * (size_t)DECn * DECn);
  u16* Wih_bf  = (u16*)alloc(sizeof(u16) * (size_t)2048 * 2560);
  u16* Whh_bf  = (u16*)alloc(sizeof(u16) * (size_t)2048 * 512);
  u16* fcw_bf  = (u16*)alloc(sizeof(u16) * (size_t)VOCABn * DECn);
  u16* emb_bf  = (u16*)alloc(sizeof(u16) * (size_t)VOCABn * EMBn);
  u16* h0w_bf  = (u16*)alloc(sizeof(u16) * (size_t)DECn * ENCn);
  u16* c0w_bf  = (u16*)alloc(sizeof(u16) * (size_t)DECn * ENCn);
  u16* avg_bf  = (u16*)alloc(sizeof(u16) * (size_t)Bn * ENCn);
  u16* hall    = (u16*)alloc(sizeof(u16) * (size_t)(Sn + 1) * Bn * DECn);
  u16* encp    = (u16*)alloc(sizeof(u16) * (size_t)Bn * Pn * ATTn);
  float* Ebuf  = (float*)alloc(sizeof(float) * (size_t)Sn * Bn * 2048);
  float* pavg  = (float*)alloc(sizeof(float) * (size_t)28 * Bn * ENCn);
  float* e_s   = (float*)alloc(sizeof(float) * (size_t)Bn * Pn);
  float* cbuf  = (float*)alloc(sizeof(float) * (size_t)Bn * DECn);
  float* p2    = (float*)alloc(sizeof(float) * (size_t)Bn * 2048);
  float* decpart = (float*)alloc(sizeof(float) * (size_t)4 * Bn * 512);

  // one-time prep
  k_cvtfeat_part<<<dim3(28, Bn), 256, 0, stream>>>(image_feat, if_bf, pavg);
  k_cvt_all<<<2048, 256, 0, stream>>>(wenc_w, wdec_w, wdec_bf,
                                      W_ih, Wih_bf, W_hh, Whh_bf,
                                      fc_w, fcw_bf, embed_w, emb_bf,
                                      h0_w, h0w_bf, c0_w, c0w_bf,
                                      Wall, wdecT, pavg, avg_bf);
  k_bigproj<<<dim3(20, 98), 256, 0, stream>>>(if_bf, Wall, wenc_b, Gbuf, encp);
  k_eproj<<<dim3(16, 10), 256, 0, stream>>>(emb_bf, captions, Wih_bf, Ebuf);
  k_h0c0<<<64, 256, 0, stream>>>(avg_bf, h0w_bf, h0_b, c0w_bf, c0_b,
                                 hall, cbuf, decpart);
  k_lin64<u16, u16, 512><<<32, 256, 0, stream>>>(hall, wdec_bf, nullptr, decpart, 512);

  for (int t = 0; t < Sn; t++) {
    const u16* hin = hall + (size_t)t * Bn * DECn;
    u16* hnew = hall + (size_t)(t + 1) * Bn * DECn;
    k_step1<<<dim3(51, Bn), 256, 0, stream>>>(encp, decpart, wdec_b, V_w, V_b, e_s,
                                              hin, Whh_bf, p2);
    k_step2<<<dim3(4, Bn), 512, 0, stream>>>(e_s, Gbuf, p2,
                                             Ebuf + (size_t)t * Bn * 2048,
                                             b_ih, b_hh, cbuf, hnew, wdecT, decpart);
  }
  k_logits<<<dim3(79, 10), 256, 0, stream>>>(hall + (size_t)Bn * DECn, fcw_bf, fc_b, out);
}